// Round 13
// baseline (5304.348 us; speedup 1.0000x reference)
//
#include <hip/hip_runtime.h>

#define T_STEPS 512
#define BB 64
#define CC 256
#define HH 1024
#define TBROWS (T_STEPS*BB)      // 32768
#define BH (BB*HH)               // 65536
#define FLSTRIDE 32              // ints per flag line (128 B)
#define RING 4                   // pA ring depth

typedef unsigned short u16;
typedef _Float16 f16;
typedef f16 f16x8 __attribute__((ext_vector_type(8)));
typedef float f32x4 __attribute__((ext_vector_type(4)));
typedef unsigned int u32x4 __attribute__((ext_vector_type(4)));
typedef unsigned int u32x2 __attribute__((ext_vector_type(2)));

__device__ __forceinline__ f32x4 mfma16h(f16x8 a, f16x8 b, f32x4 c) {
  return __builtin_amdgcn_mfma_f32_16x16x32_f16(a, b, c, 0, 0, 0);
}

__device__ __forceinline__ u16 f2h_bits(float f) {
  return __builtin_bit_cast(unsigned short, (f16)f);
}

// coherent stores: write-through to LLC (agent coherence point), cross-XCD safe
__device__ __forceinline__ void store_coh8(void* p, u32x2 v) {
  asm volatile("global_store_dwordx2 %0, %1, off sc0 sc1" :: "v"(p), "v"(v) : "memory");
}
__device__ __forceinline__ void store_coh16(void* p, u32x4 v) {
  asm volatile("global_store_dwordx4 %0, %1, off sc0 sc1" :: "v"(p), "v"(v) : "memory");
}
// coherent load (bypasses L1/L2) — for ring-reused pA slots
__device__ __forceinline__ u32x4 load_coh16(const void* p) {
  u32x4 r;
  asm volatile("global_load_dwordx4 %0, %1, off sc0 sc1" : "=v"(r) : "v"(p));
  asm volatile("s_waitcnt vmcnt(0)" ::: "memory");
  return r;
}

// per-wave slice poll: lane l checks producer 16q + (l&15); 4 lanes per line.
__device__ __forceinline__ void poll_slice(const int* step_base, int q, int lane) {
  const int* p = step_base + (size_t)(16 * q + (lane & 15)) * FLSTRIDE;
  while (true) {
    int v = __hip_atomic_load(p, __ATOMIC_RELAXED, __HIP_MEMORY_SCOPE_AGENT);
    if (__all(v != 0)) break;
    __builtin_amdgcn_s_sleep(2);
  }
}
// uniform single-line poll
__device__ __forceinline__ void poll_one(const int* p) {
  while (__hip_atomic_load(p, __ATOMIC_RELAXED, __HIP_MEMORY_SCOPE_AGENT) == 0)
    __builtin_amdgcn_s_sleep(2);
}

__global__ void sentinel_kernel(float* o, float v) { o[0] = v; }

// ---------------- fp32 -> f16 single plane ----------------
__global__ __launch_bounds__(256) void cvt_h(const float* __restrict__ src,
                                             u16* __restrict__ dst, int n4) {
  int i = blockIdx.x * 256 + threadIdx.x;
  if (i >= n4) return;
  const float4 v = ((const float4*)src)[i];
  float vv[4] = {v.x, v.y, v.z, v.w};
  uint2 o;
  o.x = (unsigned)f2h_bits(vv[0]) | ((unsigned)f2h_bits(vv[1]) << 16);
  o.y = (unsigned)f2h_bits(vv[2]) | ((unsigned)f2h_bits(vv[3]) << 16);
  ((uint2*)dst)[i] = o;
}

// ---------------- fp32 -> f16 hi + f16 (lo*2048) ----------------
__global__ __launch_bounds__(256) void split_h(const float* __restrict__ src,
                                               u16* __restrict__ hi,
                                               u16* __restrict__ lo, int n4) {
  int i = blockIdx.x * 256 + threadIdx.x;
  if (i >= n4) return;
  const float4 v = ((const float4*)src)[i];
  float vv[4] = {v.x, v.y, v.z, v.w};
  u16 h[4], l[4];
#pragma unroll
  for (int j = 0; j < 4; ++j) {
    f16 hf = (f16)vv[j];
    h[j] = __builtin_bit_cast(unsigned short, hf);
    l[j] = f2h_bits((vv[j] - (float)hf) * 2048.0f);
  }
  uint2 ho, lu;
  ho.x = (unsigned)h[0] | ((unsigned)h[1] << 16);
  ho.y = (unsigned)h[2] | ((unsigned)h[3] << 16);
  lu.x = (unsigned)l[0] | ((unsigned)l[1] << 16);
  lu.y = (unsigned)l[2] | ((unsigned)l[3] << 16);
  ((uint2*)hi)[i] = ho;
  ((uint2*)lo)[i] = lu;
}

__global__ __launch_bounds__(256) void add_bias_kernel(const float* __restrict__ a,
                                                       const float* __restrict__ b,
                                                       float* __restrict__ o, int n) {
  int i = blockIdx.x * 256 + threadIdx.x;
  if (i < n) o[i] = a[i] + b[i];
}

// ---------------- f16 GEMM: C[M,N] = A[M,K](f16) @ W[N,K](f16)^T + bias ----------------
__global__ __launch_bounds__(256) void gemmh(const u16* __restrict__ Ah,
                                             const u16* __restrict__ Wh,
                                             const float* __restrict__ bias,
                                             float* __restrict__ Cd,
                                             int M, int N, int K) {
  __shared__ u16 As[128][48];
  __shared__ u16 Bs[128][48];
  const int tid = threadIdx.x;
  const int nblk = N >> 7;
  const int mb = blockIdx.x / nblk;
  const int nb = blockIdx.x % nblk;
  const int m0 = mb << 7, n0 = nb << 7;
  const int lane = tid & 63, wave = tid >> 6;
  const int wm = (wave >> 1) * 64, wn = (wave & 1) * 64;
  const int fr = lane & 15, kg = lane >> 4;

  f32x4 acc[4][4];
#pragma unroll
  for (int i = 0; i < 4; ++i)
#pragma unroll
    for (int j = 0; j < 4; ++j) acc[i][j] = (f32x4){0.f, 0.f, 0.f, 0.f};

  const int sr = tid >> 1;
  const int sk = (tid & 1) * 16;

  for (int k0 = 0; k0 < K; k0 += 32) {
    __syncthreads();
    const size_t aoff = (size_t)(m0 + sr) * K + k0 + sk;
    *(uint4*)&As[sr][sk]     = *(const uint4*)(Ah + aoff);
    *(uint4*)&As[sr][sk + 8] = *(const uint4*)(Ah + aoff + 8);
    const size_t woff = (size_t)(n0 + sr) * K + k0 + sk;
    *(uint4*)&Bs[sr][sk]     = *(const uint4*)(Wh + woff);
    *(uint4*)&Bs[sr][sk + 8] = *(const uint4*)(Wh + woff + 8);
    __syncthreads();

    f16x8 ah[4], bh[4];
#pragma unroll
    for (int i = 0; i < 4; ++i) {
      ah[i] = *(const f16x8*)&As[wm + i * 16 + fr][kg * 8];
      bh[i] = *(const f16x8*)&Bs[wn + i * 16 + fr][kg * 8];
    }
#pragma unroll
    for (int i = 0; i < 4; ++i)
#pragma unroll
      for (int j = 0; j < 4; ++j)
        acc[i][j] = mfma16h(ah[i], bh[j], acc[i][j]);
  }

#pragma unroll
  for (int j = 0; j < 4; ++j) {
    const int n = n0 + wn + j * 16 + fr;
    const float bv = bias ? bias[n] : 0.f;
#pragma unroll
    for (int i = 0; i < 4; ++i) {
#pragma unroll
      for (int r = 0; r < 4; ++r) {
        const int m = m0 + wm + i * 16 + kg * 4 + r;
        Cd[(size_t)m * N + n] = acc[i][j][r] + bv;
      }
    }
  }
}

// ---------------- fused three-family pipelined scan ----------------
// 192 WGs x 1024 threads. fam = wg>>6: 0=L0, 1=L1A (y0@W_ih1 -> pA), 2=L1B.
// r13: (a) per-wave fine polling (wave q waits only its 16 producers; LDS gate
// deleted) -> loads start at slice readiness; (b) XCD-rotated load order:
// same-XCD WGs (xcd-local index wl>>3) start their 8-load batch at different
// positions, so each sub-block has ONE LLC-latency leader per XCD and 7 L2-hit
// followers (r12's aligned timing made all 8 pay full LLC latency per line).
__global__ __launch_bounds__(1024) void rnn_fused(
    const u16* __restrict__ whh0_hi, const u16* __restrict__ whh0_lo,
    const u16* __restrict__ wih1_hi, const u16* __restrict__ wih1_lo,
    const u16* __restrict__ whh1_hi, const u16* __restrict__ whh1_lo,
    const u16* __restrict__ cin, u16* __restrict__ cout,               // [2*BH] f16
    const float* __restrict__ xw,                                      // [nsteps,B,H] (b0 incl.)
    const float* __restrict__ b1,                                      // [H]
    u16* __restrict__ y0, u16* __restrict__ y1,                        // [nsteps,B,H] f16
    float* __restrict__ pA,                                            // [RING][B,H] f32
    float* __restrict__ hlast0, float* __restrict__ hlast1,            // [B,H] f32
    int* __restrict__ flags0, int* __restrict__ flagsA, int* __restrict__ flags1,
    int nsteps) {
  __shared__ u16 Ws[2][16][1024];      // 64 KB f16 hi/lo planes
  __shared__ f32x4 red[2][3][4][64];   // 24 KB, double-buffered by t&1
  __shared__ int pcnt;                 // producer-wave completion counter

  const int wg = blockIdx.x;
  const int fam = wg >> 6;          // 0=L0, 1=L1A, 2=L1B
  const int wl = wg & 63;
  const int n0 = wl << 4;
  const int tid = threadIdx.x;
  const int lane = tid & 63, wave = tid >> 6;
  const int q = wave >> 2;          // K-slice index
  const int g = wave & 3;           // batch group
  const int fr = lane & 15, kg = lane >> 4;
  const int rot = (wl >> 3) & 7;    // XCD-local phase (wl%8 = XCD under round-robin)

  if (tid == 2) pcnt = 0;

  // swizzled LDS address: row stride 2048B, XOR 16B slot with (row&7)
  auto wsp = [&](int hl, int r, int cbyte) -> u16* {
    return (u16*)((char*)Ws + (size_t)(hl * 16 + r) * 2048 + (cbyte ^ ((r & 7) << 4)));
  };

  {  // stage 64KB: [2][16][1024] from this family's W (hi/lo)
    const u16* whi = (fam == 0) ? whh0_hi : (fam == 1) ? wih1_hi : whh1_hi;
    const u16* wlo = (fam == 0) ? whh0_lo : (fam == 1) ? wih1_lo : whh1_lo;
#pragma unroll
    for (int j = 0; j < 4; ++j) {
      const int off = tid * 64 + j * 16;
      const int plane = off >> 15;
      const int row = (off >> 11) & 15;
      const int cbyte = off & 2047;
      const u16* src = (plane ? wlo : whi) + (size_t)(n0 + row) * HH + (cbyte >> 1);
      *(uint4*)wsp(plane, row, cbyte) = *(const uint4*)src;
    }
  }
  __syncthreads();

  const int b = (g << 4) + fr;                   // batch (B-operand col, output col)
  const int co = n0 + (kg << 2);                 // output column base (4 contiguous)
  const size_t hoff = (size_t)b * HH + q * 256 + (kg << 3);
  const int cb0 = q * 512;                       // LDS row byte base of this K-slice
  float4 bias4;
  if (fam == 1 && q == 0) bias4 = *(const float4*)(b1 + co);

  for (int t = 0; t < nsteps; ++t) {
    const size_t obase = (size_t)t * BH;
    float4 xwv;
    if (fam == 0 && q == 0) xwv = *(const float4*)(xw + obase + (size_t)b * HH + co);

    // ---- per-wave fine-grained poll: wave q waits only its 16 producers ----
    if (fam == 0) {
      if (t > 0) poll_slice(flags0 + (size_t)(t - 1) * 64 * FLSTRIDE, q, lane);
    } else if (fam == 1) {
      if (t >= RING) poll_one(flags1 + ((size_t)(t - RING) * 64 + wl) * FLSTRIDE);
      poll_slice(flags0 + (size_t)t * 64 * FLSTRIDE, q, lane);
    } else {
      if (t > 0) poll_slice(flags1 + (size_t)(t - 1) * 64 * FLSTRIDE, q, lane);
    }
    __atomic_signal_fence(__ATOMIC_ACQUIRE);

    // ---- source pointer (single f16 plane, 128 KB broadcast per WG) ----
    const u16* pb;
    if (fam == 0)      pb = ((t == 0) ? cin : (y0 + (size_t)(t - 1) * BH)) + hoff;
    else if (fam == 1) pb = y0 + obase + hoff;
    else               pb = ((t == 0) ? (cin + BH) : (y1 + (size_t)(t - 1) * BH)) + hoff;

    f32x4 acch[2], accl[2];
#pragma unroll
    for (int i = 0; i < 2; ++i) {
      acch[i] = (f32x4){0.f, 0.f, 0.f, 0.f};
      accl[i] = (f32x4){0.f, 0.f, 0.f, 0.f};
    }

    u32x4 hv8[8];
    // rotated asm-batched load phase: 8x dwordx4 in flight, one waitcnt;
    // load j fetches chunk kc=(j+rot)&7 (per-lane address add; hv8 index static)
#pragma unroll
    for (int j = 0; j < 8; ++j) {
      asm volatile("global_load_dwordx4 %0, %1, off"
                   : "=v"(hv8[j]) : "v"(pb + (((j + rot) & 7) << 5)));
    }
    asm volatile("s_waitcnt vmcnt(0)" ::: "memory");
    __builtin_amdgcn_sched_barrier(0);
#pragma unroll
    for (int j = 0; j < 8; ++j) {
      const int kc = (j + rot) & 7;               // runtime -> LDS addr only
      f16x8 hb = __builtin_bit_cast(f16x8, hv8[j]);
      const int cb = cb0 + kc * 64 + kg * 16;
      f16x8 wh = *(const f16x8*)wsp(0, fr, cb);
      f16x8 wlv = *(const f16x8*)wsp(1, fr, cb);
      const int s = j & 1;
      acch[s] = mfma16h(wh, hb, acch[s]);
      accl[s] = mfma16h(wlv, hb, accl[s]);
    }
    f32x4 accv = (acch[0] + acch[1]) + (accl[0] + accl[1]) * (1.0f / 2048.0f);

    if (q != 0) red[t & 1][q - 1][g][lane] = accv;
    __syncthreads();                              // barrier B

    if (q == 0) {
      accv = accv + red[t & 1][0][g][lane] + red[t & 1][1][g][lane] + red[t & 1][2][g][lane];

      if (fam == 1) {
        // ---- L1A epilogue: write f32 partial + b1, no tanh ----
        f32x4 o;
#pragma unroll
        for (int r = 0; r < 4; ++r) o[r] = accv[r] + ((const float*)&bias4)[r];
        store_coh16(pA + (size_t)(t & (RING - 1)) * BH + (size_t)b * HH + co,
                    __builtin_bit_cast(u32x4, o));
        asm volatile("s_waitcnt vmcnt(0)" ::: "memory");
        if (lane == 0) {
          int old = __hip_atomic_fetch_add(&pcnt, 1, __ATOMIC_ACQ_REL, __HIP_MEMORY_SCOPE_WORKGROUP);
          if (old == 3) {
            __hip_atomic_store(&pcnt, 0, __ATOMIC_RELAXED, __HIP_MEMORY_SCOPE_WORKGROUP);
            __hip_atomic_store(flagsA + ((size_t)t * 64 + wl) * FLSTRIDE, 1,
                               __ATOMIC_RELEASE, __HIP_MEMORY_SCOPE_AGENT);
          }
        }
      } else {
        float addv[4];
        if (fam == 0) {
#pragma unroll
          for (int r = 0; r < 4; ++r) addv[r] = ((const float*)&xwv)[r];
        } else {
          // L1B: wait for this WG's partial, then coherent-load it
          poll_one(flagsA + ((size_t)t * 64 + wl) * FLSTRIDE);
          u32x4 pv = load_coh16(pA + (size_t)(t & (RING - 1)) * BH + (size_t)b * HH + co);
          f32x4 pf = __builtin_bit_cast(f32x4, pv);
#pragma unroll
          for (int r = 0; r < 4; ++r) addv[r] = pf[r];
        }
        float hv[4];
        u16 qb[4];
#pragma unroll
        for (int r = 0; r < 4; ++r) {
          hv[r] = tanhf(accv[r] + addv[r]);
          qb[r] = f2h_bits(hv[r]);
        }
        const size_t oi = obase + (size_t)b * HH + co;
        u32x2 hp;
        hp.x = (unsigned)qb[0] | ((unsigned)qb[1] << 16);
        hp.y = (unsigned)qb[2] | ((unsigned)qb[3] << 16);
        store_coh8((fam == 0 ? y0 : y1) + oi, hp);
        if (t == nsteps - 1) {
          const size_t ci = (size_t)b * HH + co;
          *(u32x2*)(cout + (fam == 2 ? (size_t)BH : 0) + ci) = hp;
          *(float4*)((fam == 2 ? hlast1 : hlast0) + ci) = (float4){hv[0], hv[1], hv[2], hv[3]};
        }
        asm volatile("s_waitcnt vmcnt(0)" ::: "memory");
        if (lane == 0) {
          int old = __hip_atomic_fetch_add(&pcnt, 1, __ATOMIC_ACQ_REL, __HIP_MEMORY_SCOPE_WORKGROUP);
          if (old == 3) {
            __hip_atomic_store(&pcnt, 0, __ATOMIC_RELAXED, __HIP_MEMORY_SCOPE_WORKGROUP);
            int* fp = (fam == 0 ? flags0 : flags1) + ((size_t)t * 64 + wl) * FLSTRIDE;
            __hip_atomic_store(fp, 1, __ATOMIC_RELEASE, __HIP_MEMORY_SCOPE_AGENT);
          }
        }
      }
    }
    // famA needs barrier C (its gate doesn't include its own flags -> WAR on red)
    if (fam == 1) __syncthreads();
  }
}

// ---------------- host ----------------
struct Ptrs {
  u16 *wih0_h, *whh0_hi, *whh0_lo, *wih1_hi, *wih1_lo, *whh1_hi, *whh1_lo, *wdec_h;
  float *b0, *b1;
  u16 *carA, *carB;                             // [2*BH] f16 each
  int* flags;                                   // [3][T_STEPS][64][FLSTRIDE]
  float* pA;                                    // [RING][BH] f32
  u16 *x_h;                                     // [CT*BB*CC] f16
  float* xw;                                    // [CT*BH] f32
  u16 *y0, *y1;                                 // [CT*BH] f16
  size_t total;
};

static Ptrs make_plan(char* base, int CT) {
  Ptrs p;
  size_t off = 0;
  auto take = [&](size_t bytes) -> char* {
    off = (off + 255) & ~(size_t)255;
    char* q = base + off;
    off += bytes;
    return q;
  };
  p.wih0_h  = (u16*)take((size_t)HH * CC * 2);
  p.whh0_hi = (u16*)take((size_t)HH * HH * 2);
  p.whh0_lo = (u16*)take((size_t)HH * HH * 2);
  p.wih1_hi = (u16*)take((size_t)HH * HH * 2);
  p.wih1_lo = (u16*)take((size_t)HH * HH * 2);
  p.whh1_hi = (u16*)take((size_t)HH * HH * 2);
  p.whh1_lo = (u16*)take((size_t)HH * HH * 2);
  p.wdec_h  = (u16*)take((size_t)CC * HH * 2);
  p.b0      = (float*)take((size_t)HH * 4);
  p.b1      = (float*)take((size_t)HH * 4);
  p.carA    = (u16*)take((size_t)2 * BH * 2);
  p.carB    = (u16*)take((size_t)2 * BH * 2);
  p.flags   = (int*)take((size_t)3 * T_STEPS * 64 * FLSTRIDE * 4);
  p.pA      = (float*)take((size_t)RING * BH * 4);
  p.x_h     = (u16*)take((size_t)CT * BB * CC * 2);
  p.xw      = (float*)take((size_t)CT * BH * 4);
  p.y0      = (u16*)take((size_t)CT * BH * 2);
  p.y1      = (u16*)take((size_t)CT * BH * 2);
  p.total   = off;
  return p;
}

extern "C" void kernel_launch(void* const* d_in, const int* in_sizes, int n_in,
                              void* d_out, int out_size, void* d_ws, size_t ws_size,
                              hipStream_t stream) {
  (void)in_sizes; (void)n_in; (void)out_size;
  const float* x     = (const float*)d_in[0];
  const float* h0    = (const float*)d_in[1];
  const float* w_ih0 = (const float*)d_in[2];
  const float* w_hh0 = (const float*)d_in[3];
  const float* b_ih0 = (const float*)d_in[4];
  const float* b_hh0 = (const float*)d_in[5];
  const float* w_ih1 = (const float*)d_in[6];
  const float* w_hh1 = (const float*)d_in[7];
  const float* b_ih1 = (const float*)d_in[8];
  const float* b_hh1 = (const float*)d_in[9];
  const float* w_dec = (const float*)d_in[10];
  const float* b_dec = (const float*)d_in[11];
  float* out = (float*)d_out;

  // largest chunk CT whose plan fits ws_size
  int CT = T_STEPS;
  Ptrs P = make_plan((char*)d_ws, CT);
  while (P.total > ws_size && CT > 8) {
    CT >>= 1;
    P = make_plan((char*)d_ws, CT);
  }
  if (P.total > ws_size) {
    sentinel_kernel<<<1, 1, 0, stream>>>(out, (float)ws_size);
    return;
  }
  const int NCH = T_STEPS / CT;

  (void)hipMemsetAsync(P.flags, 0, (size_t)3 * T_STEPS * 64 * FLSTRIDE * 4, stream);

  // one-time weight/bias/h0 prep
  cvt_h<<<HH * CC / 1024, 256, 0, stream>>>(w_ih0, P.wih0_h, HH * CC / 4);
  split_h<<<HH * HH / 1024, 256, 0, stream>>>(w_hh0, P.whh0_hi, P.whh0_lo, HH * HH / 4);
  split_h<<<HH * HH / 1024, 256, 0, stream>>>(w_ih1, P.wih1_hi, P.wih1_lo, HH * HH / 4);
  split_h<<<HH * HH / 1024, 256, 0, stream>>>(w_hh1, P.whh1_hi, P.whh1_lo, HH * HH / 4);
  cvt_h<<<CC * HH / 1024, 256, 0, stream>>>(w_dec, P.wdec_h, CC * HH / 4);
  cvt_h<<<2 * BH / 1024, 256, 0, stream>>>(h0, P.carA, 2 * BH / 4);
  add_bias_kernel<<<HH / 256, 256, 0, stream>>>(b_ih0, b_hh0, P.b0, HH);
  add_bias_kernel<<<HH / 256, 256, 0, stream>>>(b_ih1, b_hh1, P.b1, HH);

  float* hlast0 = out + (size_t)TBROWS * CC;
  float* hlast1 = hlast0 + BH;

  for (int c = 0; c < NCH; ++c) {
    const int t0 = c * CT;
    const u16* cin = (c & 1) ? P.carB : P.carA;
    u16* cout = (c & 1) ? P.carA : P.carB;

    // convert x chunk to f16
    cvt_h<<<CT * BB * CC / 1024, 256, 0, stream>>>(x + (size_t)t0 * BB * CC, P.x_h,
                                                   CT * BB * CC / 4);
    // layer-0 input projection: [CT*64, 256] @ [1024,256]^T -> xw (b0 folded in)
    gemmh<<<(CT * BB / 128) * (HH / 128), 256, 0, stream>>>(P.x_h, P.wih0_h, P.b0, P.xw,
                                                            CT * BB, HH, CC);
    // fused three-family pipelined scan
    rnn_fused<<<192, 1024, 0, stream>>>(
        P.whh0_hi, P.whh0_lo, P.wih1_hi, P.wih1_lo, P.whh1_hi, P.whh1_lo,
        cin, cout, P.xw, P.b1, P.y0, P.y1, P.pA, hlast0, hlast1,
        P.flags + (size_t)t0 * 64 * FLSTRIDE,
        P.flags + (size_t)(T_STEPS + t0) * 64 * FLSTRIDE,
        P.flags + (size_t)(2 * T_STEPS + t0) * 64 * FLSTRIDE, CT);
    // decoder: [CT*64,1024] @ [256,1024]^T -> out chunk
    gemmh<<<(CT * BB / 128) * (CC / 128), 256, 0, stream>>>(P.y1, P.wdec_h, b_dec,
                                                            out + (size_t)t0 * BB * CC,
                                                            CT * BB, CC, HH);
  }
}

// Round 14
// 4922.314 us; speedup vs baseline: 1.0776x; 1.0776x over previous
//
#include <hip/hip_runtime.h>

#define T_STEPS 512
#define BB 64
#define CC 256
#define HH 1024
#define TBROWS (T_STEPS*BB)      // 32768
#define BH (BB*HH)               // 65536
#define FLSTRIDE 32              // ints per flag line (128 B)
#define FPS (8*32*FLSTRIDE)      // flag ints per step (8 xcd x 32 slots)

typedef unsigned short u16;
typedef _Float16 f16;
typedef f16 f16x8 __attribute__((ext_vector_type(8)));
typedef float f32x4 __attribute__((ext_vector_type(4)));
typedef unsigned int u32x4 __attribute__((ext_vector_type(4)));
typedef unsigned int u32x2 __attribute__((ext_vector_type(2)));

__device__ __forceinline__ f32x4 mfma16h(f16x8 a, f16x8 b, f32x4 c) {
  return __builtin_amdgcn_mfma_f32_16x16x32_f16(a, b, c, 0, 0, 0);
}
__device__ __forceinline__ u16 f2h_bits(float f) {
  return __builtin_bit_cast(unsigned short, (f16)f);
}

__global__ void sentinel_kernel(float* o, float v) { o[0] = v; }

// ---------------- fp32 -> f16 single plane ----------------
__global__ __launch_bounds__(256) void cvt_h(const float* __restrict__ src,
                                             u16* __restrict__ dst, int n4) {
  int i = blockIdx.x * 256 + threadIdx.x;
  if (i >= n4) return;
  const float4 v = ((const float4*)src)[i];
  float vv[4] = {v.x, v.y, v.z, v.w};
  uint2 o;
  o.x = (unsigned)f2h_bits(vv[0]) | ((unsigned)f2h_bits(vv[1]) << 16);
  o.y = (unsigned)f2h_bits(vv[2]) | ((unsigned)f2h_bits(vv[3]) << 16);
  ((uint2*)dst)[i] = o;
}

// ---------------- fp32 -> f16 hi + f16 (lo*2048) ----------------
__global__ __launch_bounds__(256) void split_h(const float* __restrict__ src,
                                               u16* __restrict__ hi,
                                               u16* __restrict__ lo, int n4) {
  int i = blockIdx.x * 256 + threadIdx.x;
  if (i >= n4) return;
  const float4 v = ((const float4*)src)[i];
  float vv[4] = {v.x, v.y, v.z, v.w};
  u16 h[4], l[4];
#pragma unroll
  for (int j = 0; j < 4; ++j) {
    f16 hf = (f16)vv[j];
    h[j] = __builtin_bit_cast(unsigned short, hf);
    l[j] = f2h_bits((vv[j] - (float)hf) * 2048.0f);
  }
  uint2 ho, lu;
  ho.x = (unsigned)h[0] | ((unsigned)h[1] << 16);
  ho.y = (unsigned)h[2] | ((unsigned)h[3] << 16);
  lu.x = (unsigned)l[0] | ((unsigned)l[1] << 16);
  lu.y = (unsigned)l[2] | ((unsigned)l[3] << 16);
  ((uint2*)hi)[i] = ho;
  ((uint2*)lo)[i] = lu;
}

__global__ __launch_bounds__(256) void add_bias_kernel(const float* __restrict__ a,
                                                       const float* __restrict__ b,
                                                       float* __restrict__ o, int n) {
  int i = blockIdx.x * 256 + threadIdx.x;
  if (i < n) o[i] = a[i] + b[i];
}

// ---------------- f16 GEMM: C[M,N] = A[M,K](f16) @ W[N,K](f16)^T + bias ----------------
__global__ __launch_bounds__(256) void gemmh(const u16* __restrict__ Ah,
                                             const u16* __restrict__ Wh,
                                             const float* __restrict__ bias,
                                             float* __restrict__ Cd,
                                             int M, int N, int K) {
  __shared__ u16 As[128][48];
  __shared__ u16 Bs[128][48];
  const int tid = threadIdx.x;
  const int nblk = N >> 7;
  const int mb = blockIdx.x / nblk;
  const int nb = blockIdx.x % nblk;
  const int m0 = mb << 7, n0 = nb << 7;
  const int lane = tid & 63, wave = tid >> 6;
  const int wm = (wave >> 1) * 64, wn = (wave & 1) * 64;
  const int fr = lane & 15, kg = lane >> 4;

  f32x4 acc[4][4];
#pragma unroll
  for (int i = 0; i < 4; ++i)
#pragma unroll
    for (int j = 0; j < 4; ++j) acc[i][j] = (f32x4){0.f, 0.f, 0.f, 0.f};

  const int sr = tid >> 1;
  const int sk = (tid & 1) * 16;

  for (int k0 = 0; k0 < K; k0 += 32) {
    __syncthreads();
    const size_t aoff = (size_t)(m0 + sr) * K + k0 + sk;
    *(uint4*)&As[sr][sk]     = *(const uint4*)(Ah + aoff);
    *(uint4*)&As[sr][sk + 8] = *(const uint4*)(Ah + aoff + 8);
    const size_t woff = (size_t)(n0 + sr) * K + k0 + sk;
    *(uint4*)&Bs[sr][sk]     = *(const uint4*)(Wh + woff);
    *(uint4*)&Bs[sr][sk + 8] = *(const uint4*)(Wh + woff + 8);
    __syncthreads();

    f16x8 ah[4], bh[4];
#pragma unroll
    for (int i = 0; i < 4; ++i) {
      ah[i] = *(const f16x8*)&As[wm + i * 16 + fr][kg * 8];
      bh[i] = *(const f16x8*)&Bs[wn + i * 16 + fr][kg * 8];
    }
#pragma unroll
    for (int i = 0; i < 4; ++i)
#pragma unroll
      for (int j = 0; j < 4; ++j)
        acc[i][j] = mfma16h(ah[i], bh[j], acc[i][j]);
  }

#pragma unroll
  for (int j = 0; j < 4; ++j) {
    const int n = n0 + wn + j * 16 + fr;
    const float bv = bias ? bias[n] : 0.f;
#pragma unroll
    for (int i = 0; i < 4; ++i) {
#pragma unroll
      for (int r = 0; r < 4; ++r) {
        const int m = m0 + wm + i * 16 + kg * 4 + r;
        Cd[(size_t)m * N + n] = acc[i][j][r] + bv;
      }
    }
  }
}

// ================= XCD-local scan kernels =================
// 256 WGs x 1024 threads, 1 WG/CU forced by LDS (~156 KB) -> exactly 32 WGs/XCD.
// WG claims (xcd, slot) at runtime via s_getreg(HW_REG_XCC_ID) + atomic slot claim.
// XCD x owns batches 8x..8x+8 (batch dim is parallel!); slot s owns cols 32s..+32.
// ALL scan producer->consumer hops are same-XCD: plain stores (stay in local L2)
// + vmcnt(0) + relaxed agent flag; consumers poll own-XCD flags (L2-local).

__device__ __forceinline__ int claim_role(int* claim, int* role_s, int tid) {
  if (tid == 0) {
    int xcd;
    asm volatile("s_getreg_b32 %0, hwreg(20, 0, 32)" : "=s"(xcd));  // HW_REG_XCC_ID
    xcd &= 7;
    int slot = __hip_atomic_fetch_add(claim + xcd * 32, 1, __ATOMIC_RELAXED,
                                      __HIP_MEMORY_SCOPE_AGENT) & 31;
    *role_s = xcd * 32 + slot;
  }
  __syncthreads();
  return *role_s;
}

__device__ __forceinline__ void poll_xcd(const int* base, int lane) {
  const int* p = base + (size_t)(lane & 31) * FLSTRIDE;
  while (true) {
    int v = (lane < 32) ? __hip_atomic_load(p, __ATOMIC_RELAXED, __HIP_MEMORY_SCOPE_AGENT) : 1;
    if (__all(v != 0)) break;
    __builtin_amdgcn_s_sleep(1);
  }
}

// ---- pass A: L0 scan. W_hh0 two-plane (hi + lo*2048), K=1024. ----
__global__ __launch_bounds__(1024) void rnn_scanA(
    const u16* __restrict__ Whi, const u16* __restrict__ Wlo,   // whh0 [H][H] f16 planes
    const u16* __restrict__ cin, u16* __restrict__ cout,        // [B][H] f16 (layer0)
    const float* __restrict__ xw,                               // [nsteps][B][H] f32
    u16* __restrict__ y0,                                       // [nsteps][B][H] f16
    float* __restrict__ hlast,                                  // [B][H] f32
    int* __restrict__ flags, int* __restrict__ claim, int nsteps) {
  __shared__ u16 Ws[2][32][1024];      // 128 KB
  __shared__ f32x4 red[2][2][7][64];   // 28 KB (t&1, c2, q-1, lane)
  __shared__ int role_s;

  const int tid = threadIdx.x;
  const int lane = tid & 63, wave = tid >> 6;
  const int c2 = wave & 1, q = wave >> 1;          // q: 0..7 (K=128 slice)
  const int fr = lane & 15, kg = lane >> 4;

  const int role = claim_role(claim, &role_s, tid);
  const int xcd = role >> 5, slot = role & 31;
  const int n0 = slot << 5;                        // 32 cols
  const int bb = (xcd << 3) + (fr & 7);            // global batch (fr>=8 duplicates)

  auto wsp = [&](int pl, int r, int cbyte) -> u16* {
    return (u16*)((char*)Ws + (size_t)(pl * 32 + r) * 2048 + (cbyte ^ ((r & 7) << 4)));
  };
  {  // stage 128 KB: 1024 threads x 128 B
#pragma unroll
    for (int j = 0; j < 8; ++j) {
      const int off = tid * 128 + j * 16;
      const int pl = off >> 16;
      const int row = (off >> 11) & 31;
      const int cbyte = off & 2047;
      const u16* src = (pl ? Wlo : Whi) + (size_t)(n0 + row) * HH + (cbyte >> 1);
      *(uint4*)wsp(pl, row, cbyte) = *(const uint4*)src;
    }
  }
  __syncthreads();

  const int co = n0 + c2 * 16 + (kg << 2);         // epilogue col base (q==0)
  const size_t hoff = (size_t)bb * HH + q * 128 + (kg << 3);
  const int wrow = c2 * 16 + fr;                   // W row for A-fragment

  for (int t = 0; t < nsteps; ++t) {
    const size_t obase = (size_t)t * BH;
    float4 xwv;
    if (q == 0 && fr < 8) xwv = *(const float4*)(xw + obase + (size_t)bb * HH + co);

    if (t > 0)
      poll_xcd(flags + ((size_t)(t - 1) * 8 + xcd) * 32 * FLSTRIDE, lane);
    __atomic_signal_fence(__ATOMIC_ACQUIRE);

    const u16* pb = ((t == 0) ? cin : (y0 + (size_t)(t - 1) * BH)) + hoff;

    u32x4 hv[4];
#pragma unroll
    for (int kc = 0; kc < 4; ++kc)
      asm volatile("global_load_dwordx4 %0, %1, off offset:%2"
                   : "=v"(hv[kc]) : "v"(pb), "i"(kc * 64));
    asm volatile("s_waitcnt vmcnt(0)" ::: "memory");
    __builtin_amdgcn_sched_barrier(0);

    f32x4 acch[2], accl[2];
#pragma unroll
    for (int i = 0; i < 2; ++i) {
      acch[i] = (f32x4){0.f, 0.f, 0.f, 0.f};
      accl[i] = (f32x4){0.f, 0.f, 0.f, 0.f};
    }
#pragma unroll
    for (int kc = 0; kc < 4; ++kc) {
      f16x8 hb = __builtin_bit_cast(f16x8, hv[kc]);
      const int cb = q * 256 + kc * 64 + kg * 16;
      f16x8 wh = *(const f16x8*)wsp(0, wrow, cb);
      f16x8 wl = *(const f16x8*)wsp(1, wrow, cb);
      acch[kc & 1] = mfma16h(wh, hb, acch[kc & 1]);
      accl[kc & 1] = mfma16h(wl, hb, accl[kc & 1]);
    }
    f32x4 accv = (acch[0] + acch[1]) + (accl[0] + accl[1]) * (1.0f / 2048.0f);

    if (q != 0) red[t & 1][c2][q - 1][lane] = accv;
    __syncthreads();                               // barrier B (only barrier/round)

    if (q == 0) {
#pragma unroll
      for (int i = 0; i < 7; ++i) accv += red[t & 1][c2][i][lane];
      float hvv[4]; u16 qb[4];
#pragma unroll
      for (int r = 0; r < 4; ++r) {
        hvv[r] = tanhf(accv[r] + ((const float*)&xwv)[r]);
        qb[r] = f2h_bits(hvv[r]);
      }
      if (fr < 8) {
        const size_t oi = obase + (size_t)bb * HH + co;
        u32x2 hp;
        hp.x = (unsigned)qb[0] | ((unsigned)qb[1] << 16);
        hp.y = (unsigned)qb[2] | ((unsigned)qb[3] << 16);
        *(u32x2*)(y0 + oi) = hp;                   // plain store -> local L2
        if (t == nsteps - 1) {
          *(u32x2*)(cout + (size_t)bb * HH + co) = hp;
          *(float4*)(hlast + (size_t)bb * HH + co) = (float4){hvv[0], hvv[1], hvv[2], hvv[3]};
        }
      }
      asm volatile("s_waitcnt vmcnt(0)" ::: "memory");   // y at L2
      if (lane == 0) {
        // two epilogue waves (c2=0,1); second one (odd ticket) publishes
        __shared__ int pcnt;                       // (zero-init by first use pattern below)
        if (t == 0 && c2 == 0) {}                  // placeholder
        int old = __hip_atomic_fetch_add(&pcnt, 1, __ATOMIC_ACQ_REL, __HIP_MEMORY_SCOPE_WORKGROUP);
        if (old & 1) {
          int* fp = flags + (((size_t)t * 8 + xcd) * 32 + slot) * FLSTRIDE;
          __hip_atomic_store(fp, 1, __ATOMIC_RELAXED, __HIP_MEMORY_SCOPE_AGENT);
        }
      }
    }
  }
}

// ---- pass B: L1 scan. K=2048 = [W_ih1 | W_hh1] single-plane f16. ----
// q<4 waves read y0[t] (fully materialized, no flags); q>=4 read y1[t-1] (flag-gated).
__global__ __launch_bounds__(1024) void rnn_scanB(
    const u16* __restrict__ Wih, const u16* __restrict__ Whh,   // [H][H] f16
    const u16* __restrict__ cin, u16* __restrict__ cout,        // [B][H] f16 (layer1)
    const float* __restrict__ b1,                               // [H]
    const u16* __restrict__ y0,                                 // [nsteps][B][H]
    u16* __restrict__ y1,
    float* __restrict__ hlast,
    int* __restrict__ flags, int* __restrict__ claim, int nsteps) {
  __shared__ u16 Ws[32][2048];         // 128 KB
  __shared__ f32x4 red[2][2][7][64];   // 28 KB
  __shared__ int role_s, pcnt;

  const int tid = threadIdx.x;
  const int lane = tid & 63, wave = tid >> 6;
  const int c2 = wave & 1, q = wave >> 1;          // q: 0..7 (K=256 slice)
  const int fr = lane & 15, kg = lane >> 4;

  if (tid == 2) pcnt = 0;
  const int role = claim_role(claim, &role_s, tid);
  const int xcd = role >> 5, slot = role & 31;
  const int n0 = slot << 5;
  const int bb = (xcd << 3) + (fr & 7);

  auto wsp = [&](int r, int cbyte) -> u16* {
    return (u16*)((char*)Ws + (size_t)r * 4096 + (cbyte ^ ((r & 7) << 4)));
  };
  {  // stage 128 KB: k<1024 from Wih, k>=1024 from Whh
#pragma unroll
    for (int j = 0; j < 8; ++j) {
      const int off = tid * 128 + j * 16;
      const int row = off >> 12;
      const int cbyte = off & 4095;
      const int k = cbyte >> 1;
      const u16* src = (k < 1024) ? (Wih + (size_t)(n0 + row) * HH + k)
                                  : (Whh + (size_t)(n0 + row) * HH + (k - 1024));
      *(uint4*)wsp(row, cbyte) = *(const uint4*)src;
    }
  }
  __syncthreads();

  const int co = n0 + c2 * 16 + (kg << 2);
  const size_t hoff = (size_t)bb * HH + ((q < 4) ? q * 256 : (q - 4) * 256) + (kg << 3);
  const int wrow = c2 * 16 + fr;
  float4 b1v;
  if (q == 0 && fr < 8) b1v = *(const float4*)(b1 + co);

  for (int t = 0; t < nsteps; ++t) {
    const size_t obase = (size_t)t * BH;

    if (t > 0 && q >= 4)
      poll_xcd(flags + ((size_t)(t - 1) * 8 + xcd) * 32 * FLSTRIDE, lane);
    __atomic_signal_fence(__ATOMIC_ACQUIRE);

    const u16* pb = (q < 4) ? (y0 + obase + hoff)
                            : (((t == 0) ? cin : (y1 + (size_t)(t - 1) * BH)) + hoff);

    u32x4 hv[8];
#pragma unroll
    for (int kc = 0; kc < 8; ++kc)
      asm volatile("global_load_dwordx4 %0, %1, off offset:%2"
                   : "=v"(hv[kc]) : "v"(pb), "i"(kc * 64));
    asm volatile("s_waitcnt vmcnt(0)" ::: "memory");
    __builtin_amdgcn_sched_barrier(0);

    f32x4 acc0 = (f32x4){0.f, 0.f, 0.f, 0.f}, acc1 = acc0;
#pragma unroll
    for (int kc = 0; kc < 8; ++kc) {
      f16x8 hb = __builtin_bit_cast(f16x8, hv[kc]);
      const int cb = q * 512 + kc * 64 + kg * 16;
      f16x8 wh = *(const f16x8*)wsp(wrow, cb);
      if (kc & 1) acc1 = mfma16h(wh, hb, acc1); else acc0 = mfma16h(wh, hb, acc0);
    }
    f32x4 accv = acc0 + acc1;

    if (q != 0) red[t & 1][c2][q - 1][lane] = accv;
    __syncthreads();                               // barrier B

    if (q == 0) {
#pragma unroll
      for (int i = 0; i < 7; ++i) accv += red[t & 1][c2][i][lane];
      float hvv[4]; u16 qb[4];
#pragma unroll
      for (int r = 0; r < 4; ++r) {
        hvv[r] = tanhf(accv[r] + ((const float*)&b1v)[r]);
        qb[r] = f2h_bits(hvv[r]);
      }
      if (fr < 8) {
        const size_t oi = obase + (size_t)bb * HH + co;
        u32x2 hp;
        hp.x = (unsigned)qb[0] | ((unsigned)qb[1] << 16);
        hp.y = (unsigned)qb[2] | ((unsigned)qb[3] << 16);
        *(u32x2*)(y1 + oi) = hp;
        if (t == nsteps - 1) {
          *(u32x2*)(cout + (size_t)bb * HH + co) = hp;
          *(float4*)(hlast + (size_t)bb * HH + co) = (float4){hvv[0], hvv[1], hvv[2], hvv[3]};
        }
      }
      asm volatile("s_waitcnt vmcnt(0)" ::: "memory");
      if (lane == 0) {
        int old = __hip_atomic_fetch_add(&pcnt, 1, __ATOMIC_ACQ_REL, __HIP_MEMORY_SCOPE_WORKGROUP);
        if (old & 1) {
          int* fp = flags + (((size_t)t * 8 + xcd) * 32 + slot) * FLSTRIDE;
          __hip_atomic_store(fp, 1, __ATOMIC_RELAXED, __HIP_MEMORY_SCOPE_AGENT);
        }
      }
    }
  }
}

// ---------------- host ----------------
struct Ptrs {
  u16 *wih0_h, *whh0_hi, *whh0_lo, *wih1_h, *whh1_h, *wdec_h;
  float *b0, *b1;
  u16 *carA, *carB;       // [2*BH] f16
  int* flags;             // [2*T_STEPS][FPS]
  int* claim;             // [128][8][32]
  u16 *x_h;               // [CT*BB*CC]
  float* xw;              // [CT*BH]
  u16 *y0, *y1;           // [CT*BH]
  size_t total;
};

static Ptrs make_plan(char* base, int CT) {
  Ptrs p;
  size_t off = 0;
  auto take = [&](size_t bytes) -> char* {
    off = (off + 255) & ~(size_t)255;
    char* q = base + off;
    off += bytes;
    return q;
  };
  p.wih0_h  = (u16*)take((size_t)HH * CC * 2);
  p.whh0_hi = (u16*)take((size_t)HH * HH * 2);
  p.whh0_lo = (u16*)take((size_t)HH * HH * 2);
  p.wih1_h  = (u16*)take((size_t)HH * HH * 2);
  p.whh1_h  = (u16*)take((size_t)HH * HH * 2);
  p.wdec_h  = (u16*)take((size_t)CC * HH * 2);
  p.b0      = (float*)take((size_t)HH * 4);
  p.b1      = (float*)take((size_t)HH * 4);
  p.carA    = (u16*)take((size_t)2 * BH * 2);
  p.carB    = (u16*)take((size_t)2 * BH * 2);
  p.flags   = (int*)take((size_t)2 * T_STEPS * FPS * 4);
  p.claim   = (int*)take((size_t)128 * 8 * 32 * 4);
  p.x_h     = (u16*)take((size_t)CT * BB * CC * 2);
  p.xw      = (float*)take((size_t)CT * BH * 4);
  p.y0      = (u16*)take((size_t)CT * BH * 2);
  p.y1      = (u16*)take((size_t)CT * BH * 2);
  p.total   = off;
  return p;
}

extern "C" void kernel_launch(void* const* d_in, const int* in_sizes, int n_in,
                              void* d_out, int out_size, void* d_ws, size_t ws_size,
                              hipStream_t stream) {
  (void)in_sizes; (void)n_in; (void)out_size;
  const float* x     = (const float*)d_in[0];
  const float* h0    = (const float*)d_in[1];
  const float* w_ih0 = (const float*)d_in[2];
  const float* w_hh0 = (const float*)d_in[3];
  const float* b_ih0 = (const float*)d_in[4];
  const float* b_hh0 = (const float*)d_in[5];
  const float* w_ih1 = (const float*)d_in[6];
  const float* w_hh1 = (const float*)d_in[7];
  const float* b_ih1 = (const float*)d_in[8];
  const float* b_hh1 = (const float*)d_in[9];
  const float* w_dec = (const float*)d_in[10];
  const float* b_dec = (const float*)d_in[11];
  float* out = (float*)d_out;

  int CT = T_STEPS;
  Ptrs P = make_plan((char*)d_ws, CT);
  while (P.total > ws_size && CT > 8) {
    CT >>= 1;
    P = make_plan((char*)d_ws, CT);
  }
  if (P.total > ws_size) {
    sentinel_kernel<<<1, 1, 0, stream>>>(out, (float)ws_size);
    return;
  }
  const int NCH = T_STEPS / CT;

  (void)hipMemsetAsync(P.flags, 0, (size_t)2 * T_STEPS * FPS * 4, stream);
  (void)hipMemsetAsync(P.claim, 0, (size_t)128 * 8 * 32 * 4, stream);

  // one-time weight/bias/h0 prep
  cvt_h<<<HH * CC / 1024, 256, 0, stream>>>(w_ih0, P.wih0_h, HH * CC / 4);
  split_h<<<HH * HH / 1024, 256, 0, stream>>>(w_hh0, P.whh0_hi, P.whh0_lo, HH * HH / 4);
  cvt_h<<<HH * HH / 1024, 256, 0, stream>>>(w_ih1, P.wih1_h, HH * HH / 4);
  cvt_h<<<HH * HH / 1024, 256, 0, stream>>>(w_hh1, P.whh1_h, HH * HH / 4);
  cvt_h<<<CC * HH / 1024, 256, 0, stream>>>(w_dec, P.wdec_h, CC * HH / 4);
  cvt_h<<<2 * BH / 1024, 256, 0, stream>>>(h0, P.carA, 2 * BH / 4);
  add_bias_kernel<<<HH / 256, 256, 0, stream>>>(b_ih0, b_hh0, P.b0, HH);
  add_bias_kernel<<<HH / 256, 256, 0, stream>>>(b_ih1, b_hh1, P.b1, HH);

  float* hlast0 = out + (size_t)TBROWS * CC;
  float* hlast1 = hlast0 + BH;

  for (int c = 0; c < NCH; ++c) {
    const int t0 = c * CT;
    const u16* cin = (c & 1) ? P.carB : P.carA;
    u16* cout = (c & 1) ? P.carA : P.carB;

    cvt_h<<<CT * BB * CC / 1024, 256, 0, stream>>>(x + (size_t)t0 * BB * CC, P.x_h,
                                                   CT * BB * CC / 4);
    gemmh<<<(CT * BB / 128) * (HH / 128), 256, 0, stream>>>(P.x_h, P.wih0_h, P.b0, P.xw,
                                                            CT * BB, HH, CC);
    // pass A: layer-0 scan (XCD-local)
    rnn_scanA<<<256, 1024, 0, stream>>>(
        P.whh0_hi, P.whh0_lo, cin, cout, P.xw, P.y0, hlast0,
        P.flags + (size_t)t0 * FPS, P.claim + (size_t)(2 * c) * 256, CT);
    // pass B: layer-1 scan (XCD-local; y0 fully materialized)
    rnn_scanB<<<256, 1024, 0, stream>>>(
        P.wih1_h, P.whh1_h, cin + BH, cout + BH, P.b1, P.y0, P.y1, hlast1,
        P.flags + (size_t)(T_STEPS + t0) * FPS, P.claim + (size_t)(2 * c + 1) * 256, CT);
    // decoder
    gemmh<<<(CT * BB / 128) * (CC / 128), 256, 0, stream>>>(P.y1, P.wdec_h, b_dec,
                                                            out + (size_t)t0 * BB * CC,
                                                            CT * BB, CC, HH);
  }
}

// Round 16
// 4458.964 us; speedup vs baseline: 1.1896x; 1.1039x over previous
//
#include <hip/hip_runtime.h>

#define T_STEPS 512
#define BB 64
#define CC 256
#define HH 1024
#define TBROWS (T_STEPS*BB)      // 32768
#define BH (BB*HH)               // 65536
#define FLSTRIDE 32              // ints per flag line (128 B)
#define FPS (8*32*FLSTRIDE)      // flag ints per step (8 xcd x 32 slots)

typedef unsigned short u16;
typedef _Float16 f16;
typedef f16 f16x8 __attribute__((ext_vector_type(8)));
typedef float f32x4 __attribute__((ext_vector_type(4)));
typedef unsigned int u32x4 __attribute__((ext_vector_type(4)));
typedef unsigned int u32x2 __attribute__((ext_vector_type(2)));

__device__ __forceinline__ f32x4 mfma16h(f16x8 a, f16x8 b, f32x4 c) {
  return __builtin_amdgcn_mfma_f32_16x16x32_f16(a, b, c, 0, 0, 0);
}
__device__ __forceinline__ u16 f2h_bits(float f) {
  return __builtin_bit_cast(unsigned short, (f16)f);
}

__global__ void sentinel_kernel(float* o, float v) { o[0] = v; }

// ---------------- fp32 -> f16 single plane ----------------
__global__ __launch_bounds__(256) void cvt_h(const float* __restrict__ src,
                                             u16* __restrict__ dst, int n4) {
  int i = blockIdx.x * 256 + threadIdx.x;
  if (i >= n4) return;
  const float4 v = ((const float4*)src)[i];
  float vv[4] = {v.x, v.y, v.z, v.w};
  uint2 o;
  o.x = (unsigned)f2h_bits(vv[0]) | ((unsigned)f2h_bits(vv[1]) << 16);
  o.y = (unsigned)f2h_bits(vv[2]) | ((unsigned)f2h_bits(vv[3]) << 16);
  ((uint2*)dst)[i] = o;
}

__global__ __launch_bounds__(256) void add_bias_kernel(const float* __restrict__ a,
                                                       const float* __restrict__ b,
                                                       float* __restrict__ o, int n) {
  int i = blockIdx.x * 256 + threadIdx.x;
  if (i < n) o[i] = a[i] + b[i];
}

// ---------------- f16 GEMM: C[M,N] = A[M,K](f16) @ W[N,K](f16)^T + bias ----------------
__global__ __launch_bounds__(256) void gemmh(const u16* __restrict__ Ah,
                                             const u16* __restrict__ Wh,
                                             const float* __restrict__ bias,
                                             float* __restrict__ Cd,
                                             int M, int N, int K) {
  __shared__ u16 As[128][48];
  __shared__ u16 Bs[128][48];
  const int tid = threadIdx.x;
  const int nblk = N >> 7;
  const int mb = blockIdx.x / nblk;
  const int nb = blockIdx.x % nblk;
  const int m0 = mb << 7, n0 = nb << 7;
  const int lane = tid & 63, wave = tid >> 6;
  const int wm = (wave >> 1) * 64, wn = (wave & 1) * 64;
  const int fr = lane & 15, kg = lane >> 4;

  f32x4 acc[4][4];
#pragma unroll
  for (int i = 0; i < 4; ++i)
#pragma unroll
    for (int j = 0; j < 4; ++j) acc[i][j] = (f32x4){0.f, 0.f, 0.f, 0.f};

  const int sr = tid >> 1;
  const int sk = (tid & 1) * 16;

  for (int k0 = 0; k0 < K; k0 += 32) {
    __syncthreads();
    const size_t aoff = (size_t)(m0 + sr) * K + k0 + sk;
    *(uint4*)&As[sr][sk]     = *(const uint4*)(Ah + aoff);
    *(uint4*)&As[sr][sk + 8] = *(const uint4*)(Ah + aoff + 8);
    const size_t woff = (size_t)(n0 + sr) * K + k0 + sk;
    *(uint4*)&Bs[sr][sk]     = *(const uint4*)(Wh + woff);
    *(uint4*)&Bs[sr][sk + 8] = *(const uint4*)(Wh + woff + 8);
    __syncthreads();

    f16x8 ah[4], bh[4];
#pragma unroll
    for (int i = 0; i < 4; ++i) {
      ah[i] = *(const f16x8*)&As[wm + i * 16 + fr][kg * 8];
      bh[i] = *(const f16x8*)&Bs[wn + i * 16 + fr][kg * 8];
    }
#pragma unroll
    for (int i = 0; i < 4; ++i)
#pragma unroll
      for (int j = 0; j < 4; ++j)
        acc[i][j] = mfma16h(ah[i], bh[j], acc[i][j]);
  }

#pragma unroll
  for (int j = 0; j < 4; ++j) {
    const int n = n0 + wn + j * 16 + fr;
    const float bv = bias ? bias[n] : 0.f;
#pragma unroll
    for (int i = 0; i < 4; ++i) {
#pragma unroll
      for (int r = 0; r < 4; ++r) {
        const int m = m0 + wm + i * 16 + kg * 4 + r;
        Cd[(size_t)m * N + n] = acc[i][j][r] + bv;
      }
    }
  }
}

// ================= XCD-local scan kernels =================
// 256 WGs x 1024 threads, 1 WG/CU by LDS -> 32 WGs/XCD by capacity. WG claims
// (xcd, slot) via s_getreg(HW_REG_XCC_ID) + atomic. XCD x owns batches 8x..8x+8;
// slot s owns cols 32s..+32. All scan hops same-XCD: plain stores (local L2) +
// vmcnt(0) + flag; SLICE polling — wave q polls only its K-slice's producers.

__device__ __forceinline__ int claim_role(int* claim, int* role_s, int tid) {
  if (tid == 0) {
    int xcd;
    asm volatile("s_getreg_b32 %0, hwreg(20, 0, 32)" : "=s"(xcd));  // HW_REG_XCC_ID
    xcd &= 7;
    int slot = __hip_atomic_fetch_add(claim + xcd * 32, 1, __ATOMIC_RELAXED,
                                      __HIP_MEMORY_SCOPE_AGENT) & 31;
    *role_s = xcd * 32 + slot;
  }
  __syncthreads();
  return *role_s;
}

// poll nf flag lines starting at base (lane i < nf checks line i)
__device__ __forceinline__ void poll_n(const int* base, int nf, int lane) {
  const int* p = base + (size_t)(lane & (nf - 1)) * FLSTRIDE;
  while (true) {
    int v = (lane < nf) ? __hip_atomic_load(p, __ATOMIC_RELAXED, __HIP_MEMORY_SCOPE_AGENT) : 1;
    if (__all(v != 0)) break;
    __builtin_amdgcn_s_sleep(1);
  }
}

// ---- pass A: L0 scan. W_hh0 single-plane f16, K=1024. ----
__global__ __launch_bounds__(1024) void rnn_scanA(
    const u16* __restrict__ Wh,                                 // whh0 [H][H] f16
    const u16* __restrict__ cin, u16* __restrict__ cout,        // [B][H] f16 (layer0)
    const float* __restrict__ xw,                               // [nsteps][B][H] f32
    u16* __restrict__ y0,                                       // [nsteps][B][H] f16
    float* __restrict__ hlast,                                  // [B][H] f32
    int* __restrict__ flags, int* __restrict__ claim, int nsteps) {
  __shared__ u16 Ws[32][1024];         // 64 KB single-plane
  __shared__ f32x4 red[2][2][7][64];   // 28 KB (t&1, c2, q-1, lane)
  __shared__ int role_s, pcnt;

  const int tid = threadIdx.x;
  const int lane = tid & 63, wave = tid >> 6;
  const int c2 = wave & 1, q = wave >> 1;          // q: 0..7 (K=128 slice)
  const int fr = lane & 15, kg = lane >> 4;

  if (tid == 2) pcnt = 0;
  const int role = claim_role(claim, &role_s, tid);
  const int xcd = role >> 5, slot = role & 31;
  const int n0 = slot << 5;                        // 32 cols
  const int bb = (xcd << 3) + (fr & 7);            // global batch (fr>=8 duplicates)

  auto wsp = [&](int r, int cbyte) -> u16* {
    return (u16*)((char*)Ws + (size_t)r * 2048 + (cbyte ^ ((r & 7) << 4)));
  };
  {  // stage 64 KB: 1024 threads x 64 B (r15 bug was 32 B/thread -> half of Ws
     // uninitialized -> NaN; fixed to cover all 32 rows)
#pragma unroll
    for (int j = 0; j < 4; ++j) {
      const int off = tid * 64 + j * 16;
      const int row = off >> 11;                   // 0..31
      const int cbyte = off & 2047;
      const u16* src = Wh + (size_t)(n0 + row) * HH + (cbyte >> 1);
      *(uint4*)wsp(row, cbyte) = *(const uint4*)src;
    }
  }
  __syncthreads();

  const int co = n0 + c2 * 16 + (kg << 2);         // epilogue col base (q==0)
  const size_t hoff = (size_t)bb * HH + q * 128 + (kg << 3);
  const int wrow = c2 * 16 + fr;                   // W row for A-fragment

  for (int t = 0; t < nsteps; ++t) {
    const size_t obase = (size_t)t * BH;
    float4 xwv;
    if (q == 0 && fr < 8) xwv = *(const float4*)(xw + obase + (size_t)bb * HH + co);

    // slice-poll: wave q needs cols q*128..+128 -> slots q*4..q*4+4
    if (t > 0)
      poll_n(flags + (((size_t)(t - 1) * 8 + xcd) * 32 + q * 4) * FLSTRIDE, 4, lane);
    __atomic_signal_fence(__ATOMIC_ACQUIRE);

    const u16* pb = ((t == 0) ? cin : (y0 + (size_t)(t - 1) * BH)) + hoff;

    u32x4 hv[4];
#pragma unroll
    for (int kc = 0; kc < 4; ++kc)
      asm volatile("global_load_dwordx4 %0, %1, off offset:%2"
                   : "=v"(hv[kc]) : "v"(pb), "i"(kc * 64));
    asm volatile("s_waitcnt vmcnt(0)" ::: "memory");
    __builtin_amdgcn_sched_barrier(0);

    f32x4 acc0 = (f32x4){0.f, 0.f, 0.f, 0.f}, acc1 = acc0;
#pragma unroll
    for (int kc = 0; kc < 4; ++kc) {
      f16x8 hb = __builtin_bit_cast(f16x8, hv[kc]);
      const int cb = q * 256 + kc * 64 + kg * 16;
      f16x8 wh = *(const f16x8*)wsp(wrow, cb);
      if (kc & 1) acc1 = mfma16h(wh, hb, acc1); else acc0 = mfma16h(wh, hb, acc0);
    }
    f32x4 accv = acc0 + acc1;

    if (q != 0) red[t & 1][c2][q - 1][lane] = accv;
    __syncthreads();                               // barrier B (only barrier/round)

    if (q == 0) {
#pragma unroll
      for (int i = 0; i < 7; ++i) accv += red[t & 1][c2][i][lane];
      float hvv[4]; u16 qb[4];
#pragma unroll
      for (int r = 0; r < 4; ++r) {
        hvv[r] = tanhf(accv[r] + ((const float*)&xwv)[r]);
        qb[r] = f2h_bits(hvv[r]);
      }
      if (fr < 8) {
        const size_t oi = obase + (size_t)bb * HH + co;
        u32x2 hp;
        hp.x = (unsigned)qb[0] | ((unsigned)qb[1] << 16);
        hp.y = (unsigned)qb[2] | ((unsigned)qb[3] << 16);
        *(u32x2*)(y0 + oi) = hp;                   // plain store -> local L2
        if (t == nsteps - 1) {
          *(u32x2*)(cout + (size_t)bb * HH + co) = hp;
          *(float4*)(hlast + (size_t)bb * HH + co) = (float4){hvv[0], hvv[1], hvv[2], hvv[3]};
        }
      }
      asm volatile("s_waitcnt vmcnt(0)" ::: "memory");   // y at L2
      if (lane == 0) {
        int old = __hip_atomic_fetch_add(&pcnt, 1, __ATOMIC_ACQ_REL, __HIP_MEMORY_SCOPE_WORKGROUP);
        if (old & 1) {  // second of the two c2 epilogue waves publishes
          int* fp = flags + (((size_t)t * 8 + xcd) * 32 + slot) * FLSTRIDE;
          __hip_atomic_store(fp, 1, __ATOMIC_RELAXED, __HIP_MEMORY_SCOPE_AGENT);
        }
      }
    }
  }
}

// ---- pass B: L1 scan. K=2048 = [W_ih1 | W_hh1] single-plane f16. ----
// q<4 waves read y0[t] (materialized, no poll); q>=4 read y1[t-1] (slice-poll 8).
__global__ __launch_bounds__(1024) void rnn_scanB(
    const u16* __restrict__ Wih, const u16* __restrict__ Whh,   // [H][H] f16
    const u16* __restrict__ cin, u16* __restrict__ cout,        // [B][H] f16 (layer1)
    const float* __restrict__ b1,                               // [H]
    const u16* __restrict__ y0,                                 // [nsteps][B][H]
    u16* __restrict__ y1,
    float* __restrict__ hlast,
    int* __restrict__ flags, int* __restrict__ claim, int nsteps) {
  __shared__ u16 Ws[32][2048];         // 128 KB
  __shared__ f32x4 red[2][2][7][64];   // 28 KB
  __shared__ int role_s, pcnt;

  const int tid = threadIdx.x;
  const int lane = tid & 63, wave = tid >> 6;
  const int c2 = wave & 1, q = wave >> 1;          // q: 0..7 (K=256 slice)
  const int fr = lane & 15, kg = lane >> 4;

  if (tid == 2) pcnt = 0;
  const int role = claim_role(claim, &role_s, tid);
  const int xcd = role >> 5, slot = role & 31;
  const int n0 = slot << 5;
  const int bb = (xcd << 3) + (fr & 7);

  auto wsp = [&](int r, int cbyte) -> u16* {
    return (u16*)((char*)Ws + (size_t)r * 4096 + (cbyte ^ ((r & 7) << 4)));
  };
  {  // stage 128 KB: k<1024 from Wih, k>=1024 from Whh
#pragma unroll
    for (int j = 0; j < 8; ++j) {
      const int off = tid * 128 + j * 16;
      const int row = off >> 12;
      const int cbyte = off & 4095;
      const int k = cbyte >> 1;
      const u16* src = (k < 1024) ? (Wih + (size_t)(n0 + row) * HH + k)
                                  : (Whh + (size_t)(n0 + row) * HH + (k - 1024));
      *(uint4*)wsp(row, cbyte) = *(const uint4*)src;
    }
  }
  __syncthreads();

  const int co = n0 + c2 * 16 + (kg << 2);
  const size_t hoff = (size_t)bb * HH + ((q < 4) ? q * 256 : (q - 4) * 256) + (kg << 3);
  const int wrow = c2 * 16 + fr;
  float4 b1v;
  if (q == 0 && fr < 8) b1v = *(const float4*)(b1 + co);

  for (int t = 0; t < nsteps; ++t) {
    const size_t obase = (size_t)t * BH;

    // slice-poll: wave q>=4 needs y1 cols (q-4)*256..+256 -> slots (q-4)*8..+8
    if (t > 0 && q >= 4)
      poll_n(flags + (((size_t)(t - 1) * 8 + xcd) * 32 + (q - 4) * 8) * FLSTRIDE, 8, lane);
    __atomic_signal_fence(__ATOMIC_ACQUIRE);

    const u16* pb = (q < 4) ? (y0 + obase + hoff)
                            : (((t == 0) ? cin : (y1 + (size_t)(t - 1) * BH)) + hoff);

    u32x4 hv[8];
#pragma unroll
    for (int kc = 0; kc < 8; ++kc)
      asm volatile("global_load_dwordx4 %0, %1, off offset:%2"
                   : "=v"(hv[kc]) : "v"(pb), "i"(kc * 64));
    asm volatile("s_waitcnt vmcnt(0)" ::: "memory");
    __builtin_amdgcn_sched_barrier(0);

    f32x4 acc0 = (f32x4){0.f, 0.f, 0.f, 0.f}, acc1 = acc0;
#pragma unroll
    for (int kc = 0; kc < 8; ++kc) {
      f16x8 hb = __builtin_bit_cast(f16x8, hv[kc]);
      const int cb = q * 512 + kc * 64 + kg * 16;
      f16x8 wh = *(const f16x8*)wsp(wrow, cb);
      if (kc & 1) acc1 = mfma16h(wh, hb, acc1); else acc0 = mfma16h(wh, hb, acc0);
    }
    f32x4 accv = acc0 + acc1;

    if (q != 0) red[t & 1][c2][q - 1][lane] = accv;
    __syncthreads();                               // barrier B

    if (q == 0) {
#pragma unroll
      for (int i = 0; i < 7; ++i) accv += red[t & 1][c2][i][lane];
      float hvv[4]; u16 qb[4];
#pragma unroll
      for (int r = 0; r < 4; ++r) {
        hvv[r] = tanhf(accv[r] + ((const float*)&b1v)[r]);
        qb[r] = f2h_bits(hvv[r]);
      }
      if (fr < 8) {
        const size_t oi = obase + (size_t)bb * HH + co;
        u32x2 hp;
        hp.x = (unsigned)qb[0] | ((unsigned)qb[1] << 16);
        hp.y = (unsigned)qb[2] | ((unsigned)qb[3] << 16);
        *(u32x2*)(y1 + oi) = hp;
        if (t == nsteps - 1) {
          *(u32x2*)(cout + (size_t)bb * HH + co) = hp;
          *(float4*)(hlast + (size_t)bb * HH + co) = (float4){hvv[0], hvv[1], hvv[2], hvv[3]};
        }
      }
      asm volatile("s_waitcnt vmcnt(0)" ::: "memory");
      if (lane == 0) {
        int old = __hip_atomic_fetch_add(&pcnt, 1, __ATOMIC_ACQ_REL, __HIP_MEMORY_SCOPE_WORKGROUP);
        if (old & 1) {
          int* fp = flags + (((size_t)t * 8 + xcd) * 32 + slot) * FLSTRIDE;
          __hip_atomic_store(fp, 1, __ATOMIC_RELAXED, __HIP_MEMORY_SCOPE_AGENT);
        }
      }
    }
  }
}

// ---------------- host ----------------
struct Ptrs {
  u16 *wih0_h, *whh0_h, *wih1_h, *whh1_h, *wdec_h;
  float *b0, *b1;
  u16 *carA, *carB;       // [2*BH] f16
  int* flags;             // [2*T_STEPS][FPS]
  int* claim;             // [128][8][32]
  u16 *x_h;               // [CT*BB*CC]
  float* xw;              // [CT*BH]
  u16 *y0, *y1;           // [CT*BH]
  size_t total;
};

static Ptrs make_plan(char* base, int CT) {
  Ptrs p;
  size_t off = 0;
  auto take = [&](size_t bytes) -> char* {
    off = (off + 255) & ~(size_t)255;
    char* q = base + off;
    off += bytes;
    return q;
  };
  p.wih0_h  = (u16*)take((size_t)HH * CC * 2);
  p.whh0_h  = (u16*)take((size_t)HH * HH * 2);
  p.wih1_h  = (u16*)take((size_t)HH * HH * 2);
  p.whh1_h  = (u16*)take((size_t)HH * HH * 2);
  p.wdec_h  = (u16*)take((size_t)CC * HH * 2);
  p.b0      = (float*)take((size_t)HH * 4);
  p.b1      = (float*)take((size_t)HH * 4);
  p.carA    = (u16*)take((size_t)2 * BH * 2);
  p.carB    = (u16*)take((size_t)2 * BH * 2);
  p.flags   = (int*)take((size_t)2 * T_STEPS * FPS * 4);
  p.claim   = (int*)take((size_t)128 * 8 * 32 * 4);
  p.x_h     = (u16*)take((size_t)CT * BB * CC * 2);
  p.xw      = (float*)take((size_t)CT * BH * 4);
  p.y0      = (u16*)take((size_t)CT * BH * 2);
  p.y1      = (u16*)take((size_t)CT * BH * 2);
  p.total   = off;
  return p;
}

extern "C" void kernel_launch(void* const* d_in, const int* in_sizes, int n_in,
                              void* d_out, int out_size, void* d_ws, size_t ws_size,
                              hipStream_t stream) {
  (void)in_sizes; (void)n_in; (void)out_size;
  const float* x     = (const float*)d_in[0];
  const float* h0    = (const float*)d_in[1];
  const float* w_ih0 = (const float*)d_in[2];
  const float* w_hh0 = (const float*)d_in[3];
  const float* b_ih0 = (const float*)d_in[4];
  const float* b_hh0 = (const float*)d_in[5];
  const float* w_ih1 = (const float*)d_in[6];
  const float* w_hh1 = (const float*)d_in[7];
  const float* b_ih1 = (const float*)d_in[8];
  const float* b_hh1 = (const float*)d_in[9];
  const float* w_dec = (const float*)d_in[10];
  const float* b_dec = (const float*)d_in[11];
  float* out = (float*)d_out;

  int CT = T_STEPS;
  Ptrs P = make_plan((char*)d_ws, CT);
  while (P.total > ws_size && CT > 8) {
    CT >>= 1;
    P = make_plan((char*)d_ws, CT);
  }
  if (P.total > ws_size) {
    sentinel_kernel<<<1, 1, 0, stream>>>(out, (float)ws_size);
    return;
  }
  const int NCH = T_STEPS / CT;

  (void)hipMemsetAsync(P.flags, 0, (size_t)2 * T_STEPS * FPS * 4, stream);
  (void)hipMemsetAsync(P.claim, 0, (size_t)128 * 8 * 32 * 4, stream);

  // one-time weight/bias/h0 prep (all single-plane f16)
  cvt_h<<<HH * CC / 1024, 256, 0, stream>>>(w_ih0, P.wih0_h, HH * CC / 4);
  cvt_h<<<HH * HH / 1024, 256, 0, stream>>>(w_hh0, P.whh0_h, HH * HH / 4);
  cvt_h<<<HH * HH / 1024, 256, 0, stream>>>(w_ih1, P.wih1_h, HH * HH / 4);
  cvt_h<<<HH * HH / 1024, 256, 0, stream>>>(w_hh1, P.whh1_h, HH * HH / 4);
  cvt_h<<<CC * HH / 1024, 256, 0, stream>>>(w_dec, P.wdec_h, CC * HH / 4);
  cvt_h<<<2 * BH / 1024, 256, 0, stream>>>(h0, P.carA, 2 * BH / 4);
  add_bias_kernel<<<HH / 256, 256, 0, stream>>>(b_ih0, b_hh0, P.b0, HH);
  add_bias_kernel<<<HH / 256, 256, 0, stream>>>(b_ih1, b_hh1, P.b1, HH);

  float* hlast0 = out + (size_t)TBROWS * CC;
  float* hlast1 = hlast0 + BH;

  for (int c = 0; c < NCH; ++c) {
    const int t0 = c * CT;
    const u16* cin = (c & 1) ? P.carB : P.carA;
    u16* cout = (c & 1) ? P.carA : P.carB;

    cvt_h<<<CT * BB * CC / 1024, 256, 0, stream>>>(x + (size_t)t0 * BB * CC, P.x_h,
                                                   CT * BB * CC / 4);
    gemmh<<<(CT * BB / 128) * (HH / 128), 256, 0, stream>>>(P.x_h, P.wih0_h, P.b0, P.xw,
                                                            CT * BB, HH, CC);
    // pass A: layer-0 scan (XCD-local, single-plane W, slice-poll)
    rnn_scanA<<<256, 1024, 0, stream>>>(
        P.whh0_h, cin, cout, P.xw, P.y0, hlast0,
        P.flags + (size_t)t0 * FPS, P.claim + (size_t)(2 * c) * 256, CT);
    // pass B: layer-1 scan (XCD-local; y0 fully materialized; slice-poll)
    rnn_scanB<<<256, 1024, 0, stream>>>(
        P.wih1_h, P.whh1_h, cin + BH, cout + BH, P.b1, P.y0, P.y1, hlast1,
        P.flags + (size_t)(T_STEPS + t0) * FPS, P.claim + (size_t)(2 * c + 1) * 256, CT);
    // decoder
    gemmh<<<(CT * BB / 128) * (CC / 128), 256, 0, stream>>>(P.y1, P.wdec_h, b_dec,
                                                            out + (size_t)t0 * BB * CC,
                                                            CT * BB, CC, HH);
  }
}

// Round 17
// 4360.976 us; speedup vs baseline: 1.2163x; 1.0225x over previous
//
#include <hip/hip_runtime.h>

#define T_STEPS 512
#define BB 64
#define CC 256
#define HH 1024
#define TBROWS (T_STEPS*BB)      // 32768
#define BH (BB*HH)               // 65536
#define FLSTRIDE 32              // ints per flag line (128 B)
#define FPS (8*32*FLSTRIDE)      // flag ints per step (8 xcd x 32 slots)

typedef unsigned short u16;
typedef _Float16 f16;
typedef f16 f16x8 __attribute__((ext_vector_type(8)));
typedef float f32x4 __attribute__((ext_vector_type(4)));
typedef unsigned int u32x4 __attribute__((ext_vector_type(4)));
typedef unsigned int u32x2 __attribute__((ext_vector_type(2)));

__device__ __forceinline__ f32x4 mfma16h(f16x8 a, f16x8 b, f32x4 c) {
  return __builtin_amdgcn_mfma_f32_16x16x32_f16(a, b, c, 0, 0, 0);
}
__device__ __forceinline__ u16 f2h_bits(float f) {
  return __builtin_bit_cast(unsigned short, (f16)f);
}

__global__ void sentinel_kernel(float* o, float v) { o[0] = v; }

// ---------------- fp32 -> f16 single plane ----------------
__global__ __launch_bounds__(256) void cvt_h(const float* __restrict__ src,
                                             u16* __restrict__ dst, int n4) {
  int i = blockIdx.x * 256 + threadIdx.x;
  if (i >= n4) return;
  const float4 v = ((const float4*)src)[i];
  float vv[4] = {v.x, v.y, v.z, v.w};
  uint2 o;
  o.x = (unsigned)f2h_bits(vv[0]) | ((unsigned)f2h_bits(vv[1]) << 16);
  o.y = (unsigned)f2h_bits(vv[2]) | ((unsigned)f2h_bits(vv[3]) << 16);
  ((uint2*)dst)[i] = o;
}

__global__ __launch_bounds__(256) void add_bias_kernel(const float* __restrict__ a,
                                                       const float* __restrict__ b,
                                                       float* __restrict__ o, int n) {
  int i = blockIdx.x * 256 + threadIdx.x;
  if (i < n) o[i] = a[i] + b[i];
}

// ---------------- f16 GEMM: C[M,N] = A[M,K](f16) @ W[N,K](f16)^T + bias ----------------
__global__ __launch_bounds__(256) void gemmh(const u16* __restrict__ Ah,
                                             const u16* __restrict__ Wh,
                                             const float* __restrict__ bias,
                                             float* __restrict__ Cd,
                                             int M, int N, int K) {
  __shared__ u16 As[128][48];
  __shared__ u16 Bs[128][48];
  const int tid = threadIdx.x;
  const int nblk = N >> 7;
  const int mb = blockIdx.x / nblk;
  const int nb = blockIdx.x % nblk;
  const int m0 = mb << 7, n0 = nb << 7;
  const int lane = tid & 63, wave = tid >> 6;
  const int wm = (wave >> 1) * 64, wn = (wave & 1) * 64;
  const int fr = lane & 15, kg = lane >> 4;

  f32x4 acc[4][4];
#pragma unroll
  for (int i = 0; i < 4; ++i)
#pragma unroll
    for (int j = 0; j < 4; ++j) acc[i][j] = (f32x4){0.f, 0.f, 0.f, 0.f};

  const int sr = tid >> 1;
  const int sk = (tid & 1) * 16;

  for (int k0 = 0; k0 < K; k0 += 32) {
    __syncthreads();
    const size_t aoff = (size_t)(m0 + sr) * K + k0 + sk;
    *(uint4*)&As[sr][sk]     = *(const uint4*)(Ah + aoff);
    *(uint4*)&As[sr][sk + 8] = *(const uint4*)(Ah + aoff + 8);
    const size_t woff = (size_t)(n0 + sr) * K + k0 + sk;
    *(uint4*)&Bs[sr][sk]     = *(const uint4*)(Wh + woff);
    *(uint4*)&Bs[sr][sk + 8] = *(const uint4*)(Wh + woff + 8);
    __syncthreads();

    f16x8 ah[4], bh[4];
#pragma unroll
    for (int i = 0; i < 4; ++i) {
      ah[i] = *(const f16x8*)&As[wm + i * 16 + fr][kg * 8];
      bh[i] = *(const f16x8*)&Bs[wn + i * 16 + fr][kg * 8];
    }
#pragma unroll
    for (int i = 0; i < 4; ++i)
#pragma unroll
      for (int j = 0; j < 4; ++j)
        acc[i][j] = mfma16h(ah[i], bh[j], acc[i][j]);
  }

#pragma unroll
  for (int j = 0; j < 4; ++j) {
    const int n = n0 + wn + j * 16 + fr;
    const float bv = bias ? bias[n] : 0.f;
#pragma unroll
    for (int i = 0; i < 4; ++i) {
#pragma unroll
      for (int r = 0; r < 4; ++r) {
        const int m = m0 + wm + i * 16 + kg * 4 + r;
        Cd[(size_t)m * N + n] = acc[i][j][r] + bv;
      }
    }
  }
}

// ================= XCD-local scan kernels =================
// 256 WGs x 1024 threads, 1 WG/CU by LDS -> 32 WGs/XCD by capacity. WG claims
// (xcd, slot) via s_getreg(HW_REG_XCC_ID) + atomic. XCD x owns batches 8x..8x+8;
// slot s owns cols 32s..+32. All scan hops same-XCD: plain stores (local L2) +
// vmcnt(0) + flag; SLICE polling — wave q polls only its K-slice's producers.

__device__ __forceinline__ int claim_role(int* claim, int* role_s, int tid) {
  if (tid == 0) {
    int xcd;
    asm volatile("s_getreg_b32 %0, hwreg(20, 0, 32)" : "=s"(xcd));  // HW_REG_XCC_ID
    xcd &= 7;
    int slot = __hip_atomic_fetch_add(claim + xcd * 32, 1, __ATOMIC_RELAXED,
                                      __HIP_MEMORY_SCOPE_AGENT) & 31;
    *role_s = xcd * 32 + slot;
  }
  __syncthreads();
  return *role_s;
}

// poll nf flag lines starting at base (lane i < nf checks line i)
__device__ __forceinline__ void poll_n(const int* base, int nf, int lane) {
  const int* p = base + (size_t)(lane & (nf - 1)) * FLSTRIDE;
  while (true) {
    int v = (lane < nf) ? __hip_atomic_load(p, __ATOMIC_RELAXED, __HIP_MEMORY_SCOPE_AGENT) : 1;
    if (__all(v != 0)) break;
    __builtin_amdgcn_s_sleep(1);
  }
}

// issue 8x16B loads (stay in flight until an explicit vmcnt)
__device__ __forceinline__ void issue8(u32x4 (&hv)[8], const u16* pb) {
#pragma unroll
  for (int kc = 0; kc < 8; ++kc)
    asm volatile("global_load_dwordx4 %0, %1, off offset:%2"
                 : "=v"(hv[kc]) : "v"(pb), "i"(kc * 64));
}

// ---- pass A: L0 scan. W_hh0 single-plane f16, K=1024. ----
__global__ __launch_bounds__(1024) void rnn_scanA(
    const u16* __restrict__ Wh,                                 // whh0 [H][H] f16
    const u16* __restrict__ cin, u16* __restrict__ cout,        // [B][H] f16 (layer0)
    const float* __restrict__ xw,                               // [nsteps][B][H] f32
    u16* __restrict__ y0,                                       // [nsteps][B][H] f16
    float* __restrict__ hlast,                                  // [B][H] f32
    int* __restrict__ flags, int* __restrict__ claim, int nsteps) {
  __shared__ u16 Ws[32][1024];         // 64 KB single-plane
  __shared__ f32x4 red[2][2][7][64];   // 28 KB (t&1, c2, q-1, lane)
  __shared__ int role_s, pcnt;

  const int tid = threadIdx.x;
  const int lane = tid & 63, wave = tid >> 6;
  const int c2 = wave & 1, q = wave >> 1;          // q: 0..7 (K=128 slice)
  const int fr = lane & 15, kg = lane >> 4;

  if (tid == 2) pcnt = 0;
  const int role = claim_role(claim, &role_s, tid);
  const int xcd = role >> 5, slot = role & 31;
  const int n0 = slot << 5;                        // 32 cols
  const int bb = (xcd << 3) + (fr & 7);            // global batch (fr>=8 duplicates)

  auto wsp = [&](int r, int cbyte) -> u16* {
    return (u16*)((char*)Ws + (size_t)r * 2048 + (cbyte ^ ((r & 7) << 4)));
  };
  {  // stage 64 KB: 1024 threads x 64 B
#pragma unroll
    for (int j = 0; j < 4; ++j) {
      const int off = tid * 64 + j * 16;
      const int row = off >> 11;                   // 0..31
      const int cbyte = off & 2047;
      const u16* src = Wh + (size_t)(n0 + row) * HH + (cbyte >> 1);
      *(uint4*)wsp(row, cbyte) = *(const uint4*)src;
    }
  }
  __syncthreads();

  const int co = n0 + c2 * 16 + (kg << 2);         // epilogue col base (q==0)
  const size_t hoff = (size_t)bb * HH + q * 128 + (kg << 3);
  const int wrow = c2 * 16 + fr;                   // W row for A-fragment

  for (int t = 0; t < nsteps; ++t) {
    const size_t obase = (size_t)t * BH;
    float4 xwv;
    if (q == 0 && fr < 8) xwv = *(const float4*)(xw + obase + (size_t)bb * HH + co);

    // slice-poll: wave q needs cols q*128..+128 -> slots q*4..q*4+4
    if (t > 0)
      poll_n(flags + (((size_t)(t - 1) * 8 + xcd) * 32 + q * 4) * FLSTRIDE, 4, lane);
    __atomic_signal_fence(__ATOMIC_ACQUIRE);

    const u16* pb = ((t == 0) ? cin : (y0 + (size_t)(t - 1) * BH)) + hoff;

    u32x4 hv[4];
#pragma unroll
    for (int kc = 0; kc < 4; ++kc)
      asm volatile("global_load_dwordx4 %0, %1, off offset:%2"
                   : "=v"(hv[kc]) : "v"(pb), "i"(kc * 64));
    asm volatile("s_waitcnt vmcnt(0)" ::: "memory");
    __builtin_amdgcn_sched_barrier(0);

    f32x4 acc0 = (f32x4){0.f, 0.f, 0.f, 0.f}, acc1 = acc0;
#pragma unroll
    for (int kc = 0; kc < 4; ++kc) {
      f16x8 hb = __builtin_bit_cast(f16x8, hv[kc]);
      const int cb = q * 256 + kc * 64 + kg * 16;
      f16x8 wh = *(const f16x8*)wsp(wrow, cb);
      if (kc & 1) acc1 = mfma16h(wh, hb, acc1); else acc0 = mfma16h(wh, hb, acc0);
    }
    f32x4 accv = acc0 + acc1;

    if (q != 0) red[t & 1][c2][q - 1][lane] = accv;
    __syncthreads();                               // barrier B (only barrier/round)

    if (q == 0) {
#pragma unroll
      for (int i = 0; i < 7; ++i) accv += red[t & 1][c2][i][lane];
      float hvv[4]; u16 qb[4];
#pragma unroll
      for (int r = 0; r < 4; ++r) {
        hvv[r] = tanhf(accv[r] + ((const float*)&xwv)[r]);
        qb[r] = f2h_bits(hvv[r]);
      }
      if (fr < 8) {
        const size_t oi = obase + (size_t)bb * HH + co;
        u32x2 hp;
        hp.x = (unsigned)qb[0] | ((unsigned)qb[1] << 16);
        hp.y = (unsigned)qb[2] | ((unsigned)qb[3] << 16);
        *(u32x2*)(y0 + oi) = hp;                   // plain store -> local L2
        if (t == nsteps - 1) {
          *(u32x2*)(cout + (size_t)bb * HH + co) = hp;
          *(float4*)(hlast + (size_t)bb * HH + co) = (float4){hvv[0], hvv[1], hvv[2], hvv[3]};
        }
      }
      asm volatile("s_waitcnt vmcnt(0)" ::: "memory");   // y at L2
      if (lane == 0) {
        int old = __hip_atomic_fetch_add(&pcnt, 1, __ATOMIC_ACQ_REL, __HIP_MEMORY_SCOPE_WORKGROUP);
        if (old & 1) {  // second of the two c2 epilogue waves publishes
          int* fp = flags + (((size_t)t * 8 + xcd) * 32 + slot) * FLSTRIDE;
          __hip_atomic_store(fp, 1, __ATOMIC_RELAXED, __HIP_MEMORY_SCOPE_AGENT);
        }
      }
    }
  }
}

// ---- pass B: L1 scan. K=2048 = [W_ih1 | W_hh1] single-plane f16. ----
// q<4 waves read y0[t] (materialized): r17 SOFTWARE-PIPELINED — step t+1's y0
// loads issue right after step t's MFMAs (before barrier B), hiding HBM latency
// under the y1-side waves' poll+load (r16 paid ~900cy HBM latency per round).
// q>=4 read y1[t-1] (slice-poll 8, dependency-gated, unchanged).
__global__ __launch_bounds__(1024) void rnn_scanB(
    const u16* __restrict__ Wih, const u16* __restrict__ Whh,   // [H][H] f16
    const u16* __restrict__ cin, u16* __restrict__ cout,        // [B][H] f16 (layer1)
    const float* __restrict__ b1,                               // [H]
    const u16* __restrict__ y0,                                 // [nsteps][B][H]
    u16* __restrict__ y1,
    float* __restrict__ hlast,
    int* __restrict__ flags, int* __restrict__ claim, int nsteps) {
  __shared__ u16 Ws[32][2048];         // 128 KB
  __shared__ f32x4 red[2][2][7][64];   // 28 KB
  __shared__ int role_s, pcnt;

  const int tid = threadIdx.x;
  const int lane = tid & 63, wave = tid >> 6;
  const int c2 = wave & 1, q = wave >> 1;          // q: 0..7 (K=256 slice)
  const int fr = lane & 15, kg = lane >> 4;

  if (tid == 2) pcnt = 0;
  const int role = claim_role(claim, &role_s, tid);
  const int xcd = role >> 5, slot = role & 31;
  const int n0 = slot << 5;
  const int bb = (xcd << 3) + (fr & 7);

  auto wsp = [&](int r, int cbyte) -> u16* {
    return (u16*)((char*)Ws + (size_t)r * 4096 + (cbyte ^ ((r & 7) << 4)));
  };
  {  // stage 128 KB: k<1024 from Wih, k>=1024 from Whh
#pragma unroll
    for (int j = 0; j < 8; ++j) {
      const int off = tid * 128 + j * 16;
      const int row = off >> 12;
      const int cbyte = off & 4095;
      const int k = cbyte >> 1;
      const u16* src = (k < 1024) ? (Wih + (size_t)(n0 + row) * HH + k)
                                  : (Whh + (size_t)(n0 + row) * HH + (k - 1024));
      *(uint4*)wsp(row, cbyte) = *(const uint4*)src;
    }
  }
  __syncthreads();

  const int co = n0 + c2 * 16 + (kg << 2);
  const size_t hoff = (size_t)bb * HH + ((q < 4) ? q * 256 : (q - 4) * 256) + (kg << 3);
  const int wrow = c2 * 16 + fr;
  float4 b1v;
  if (q == 0 && fr < 8) b1v = *(const float4*)(b1 + co);

  u32x4 hvA[8], hvB[8];
  if (q < 4) issue8(hvA, y0 + hoff);               // prefetch t=0

  auto step = [&](int t, u32x4 (&hvc)[8], u32x4 (&hvn)[8]) {
    const size_t obase = (size_t)t * BH;

    if (q >= 4) {
      // slice-poll: wave q needs y1 cols (q-4)*256..+256 -> slots (q-4)*8..+8
      if (t > 0)
        poll_n(flags + (((size_t)(t - 1) * 8 + xcd) * 32 + (q - 4) * 8) * FLSTRIDE, 8, lane);
      __atomic_signal_fence(__ATOMIC_ACQUIRE);
      const u16* pb = ((t == 0) ? cin : (y1 + (size_t)(t - 1) * BH)) + hoff;
      issue8(hvc, pb);
    }
    asm volatile("s_waitcnt vmcnt(0)" ::: "memory");
    __builtin_amdgcn_sched_barrier(0);

    f32x4 acc0 = (f32x4){0.f, 0.f, 0.f, 0.f}, acc1 = acc0;
#pragma unroll
    for (int kc = 0; kc < 8; ++kc) {
      f16x8 hb = __builtin_bit_cast(f16x8, hvc[kc]);
      const int cb = q * 512 + kc * 64 + kg * 16;
      f16x8 wh = *(const f16x8*)wsp(wrow, cb);
      if (kc & 1) acc1 = mfma16h(wh, hb, acc1); else acc0 = mfma16h(wh, hb, acc0);
    }
    f32x4 accv = acc0 + acc1;

    // prefetch next step's y0 (dependency-free; latency hides under y1-side path)
    if (q < 4 && t + 1 < nsteps) issue8(hvn, y0 + (size_t)(t + 1) * BH + hoff);

    if (q != 0) red[t & 1][c2][q - 1][lane] = accv;
    __syncthreads();                               // barrier B

    if (q == 0) {
#pragma unroll
      for (int i = 0; i < 7; ++i) accv += red[t & 1][c2][i][lane];
      float hvv[4]; u16 qb[4];
#pragma unroll
      for (int r = 0; r < 4; ++r) {
        hvv[r] = tanhf(accv[r] + ((const float*)&b1v)[r]);
        qb[r] = f2h_bits(hvv[r]);
      }
      if (fr < 8) {
        const size_t oi = obase + (size_t)bb * HH + co;
        u32x2 hp;
        hp.x = (unsigned)qb[0] | ((unsigned)qb[1] << 16);
        hp.y = (unsigned)qb[2] | ((unsigned)qb[3] << 16);
        *(u32x2*)(y1 + oi) = hp;
        if (t == nsteps - 1) {
          *(u32x2*)(cout + (size_t)bb * HH + co) = hp;
          *(float4*)(hlast + (size_t)bb * HH + co) = (float4){hvv[0], hvv[1], hvv[2], hvv[3]};
        }
      }
      asm volatile("s_waitcnt vmcnt(0)" ::: "memory");
      if (lane == 0) {
        int old = __hip_atomic_fetch_add(&pcnt, 1, __ATOMIC_ACQ_REL, __HIP_MEMORY_SCOPE_WORKGROUP);
        if (old & 1) {
          int* fp = flags + (((size_t)t * 8 + xcd) * 32 + slot) * FLSTRIDE;
          __hip_atomic_store(fp, 1, __ATOMIC_RELAXED, __HIP_MEMORY_SCOPE_AGENT);
        }
      }
    }
  };

  for (int t = 0; t < nsteps; t += 2) {
    step(t, hvA, hvB);
    step(t + 1, hvB, hvA);
  }
}

// ---------------- host ----------------
struct Ptrs {
  u16 *wih0_h, *whh0_h, *wih1_h, *whh1_h, *wdec_h;
  float *b0, *b1;
  u16 *carA, *carB;       // [2*BH] f16
  int* flags;             // [2*T_STEPS][FPS]
  int* claim;             // [128][8][32]
  u16 *x_h;               // [CT*BB*CC]
  float* xw;              // [CT*BH]
  u16 *y0, *y1;           // [CT*BH]
  size_t total;
};

static Ptrs make_plan(char* base, int CT) {
  Ptrs p;
  size_t off = 0;
  auto take = [&](size_t bytes) -> char* {
    off = (off + 255) & ~(size_t)255;
    char* q = base + off;
    off += bytes;
    return q;
  };
  p.wih0_h  = (u16*)take((size_t)HH * CC * 2);
  p.whh0_h  = (u16*)take((size_t)HH * HH * 2);
  p.wih1_h  = (u16*)take((size_t)HH * HH * 2);
  p.whh1_h  = (u16*)take((size_t)HH * HH * 2);
  p.wdec_h  = (u16*)take((size_t)CC * HH * 2);
  p.b0      = (float*)take((size_t)HH * 4);
  p.b1      = (float*)take((size_t)HH * 4);
  p.carA    = (u16*)take((size_t)2 * BH * 2);
  p.carB    = (u16*)take((size_t)2 * BH * 2);
  p.flags   = (int*)take((size_t)2 * T_STEPS * FPS * 4);
  p.claim   = (int*)take((size_t)128 * 8 * 32 * 4);
  p.x_h     = (u16*)take((size_t)CT * BB * CC * 2);
  p.xw      = (float*)take((size_t)CT * BH * 4);
  p.y0      = (u16*)take((size_t)CT * BH * 2);
  p.y1      = (u16*)take((size_t)CT * BH * 2);
  p.total   = off;
  return p;
}

extern "C" void kernel_launch(void* const* d_in, const int* in_sizes, int n_in,
                              void* d_out, int out_size, void* d_ws, size_t ws_size,
                              hipStream_t stream) {
  (void)in_sizes; (void)n_in; (void)out_size;
  const float* x     = (const float*)d_in[0];
  const float* h0    = (const float*)d_in[1];
  const float* w_ih0 = (const float*)d_in[2];
  const float* w_hh0 = (const float*)d_in[3];
  const float* b_ih0 = (const float*)d_in[4];
  const float* b_hh0 = (const float*)d_in[5];
  const float* w_ih1 = (const float*)d_in[6];
  const float* w_hh1 = (const float*)d_in[7];
  const float* b_ih1 = (const float*)d_in[8];
  const float* b_hh1 = (const float*)d_in[9];
  const float* w_dec = (const float*)d_in[10];
  const float* b_dec = (const float*)d_in[11];
  float* out = (float*)d_out;

  int CT = T_STEPS;
  Ptrs P = make_plan((char*)d_ws, CT);
  while (P.total > ws_size && CT > 8) {
    CT >>= 1;
    P = make_plan((char*)d_ws, CT);
  }
  if (P.total > ws_size) {
    sentinel_kernel<<<1, 1, 0, stream>>>(out, (float)ws_size);
    return;
  }
  const int NCH = T_STEPS / CT;

  (void)hipMemsetAsync(P.flags, 0, (size_t)2 * T_STEPS * FPS * 4, stream);
  (void)hipMemsetAsync(P.claim, 0, (size_t)128 * 8 * 32 * 4, stream);

  // one-time weight/bias/h0 prep (all single-plane f16)
  cvt_h<<<HH * CC / 1024, 256, 0, stream>>>(w_ih0, P.wih0_h, HH * CC / 4);
  cvt_h<<<HH * HH / 1024, 256, 0, stream>>>(w_hh0, P.whh0_h, HH * HH / 4);
  cvt_h<<<HH * HH / 1024, 256, 0, stream>>>(w_ih1, P.wih1_h, HH * HH / 4);
  cvt_h<<<HH * HH / 1024, 256, 0, stream>>>(w_hh1, P.whh1_h, HH * HH / 4);
  cvt_h<<<CC * HH / 1024, 256, 0, stream>>>(w_dec, P.wdec_h, CC * HH / 4);
  cvt_h<<<2 * BH / 1024, 256, 0, stream>>>(h0, P.carA, 2 * BH / 4);
  add_bias_kernel<<<HH / 256, 256, 0, stream>>>(b_ih0, b_hh0, P.b0, HH);
  add_bias_kernel<<<HH / 256, 256, 0, stream>>>(b_ih1, b_hh1, P.b1, HH);

  float* hlast0 = out + (size_t)TBROWS * CC;
  float* hlast1 = hlast0 + BH;

  for (int c = 0; c < NCH; ++c) {
    const int t0 = c * CT;
    const u16* cin = (c & 1) ? P.carB : P.carA;
    u16* cout = (c & 1) ? P.carA : P.carB;

    cvt_h<<<CT * BB * CC / 1024, 256, 0, stream>>>(x + (size_t)t0 * BB * CC, P.x_h,
                                                   CT * BB * CC / 4);
    gemmh<<<(CT * BB / 128) * (HH / 128), 256, 0, stream>>>(P.x_h, P.wih0_h, P.b0, P.xw,
                                                            CT * BB, HH, CC);
    // pass A: layer-0 scan (XCD-local, single-plane W, slice-poll)
    rnn_scanA<<<256, 1024, 0, stream>>>(
        P.whh0_h, cin, cout, P.xw, P.y0, hlast0,
        P.flags + (size_t)t0 * FPS, P.claim + (size_t)(2 * c) * 256, CT);
    // pass B: layer-1 scan (XCD-local; y0 prefetch-pipelined; slice-poll)
    rnn_scanB<<<256, 1024, 0, stream>>>(
        P.wih1_h, P.whh1_h, cin + BH, cout + BH, P.b1, P.y0, P.y1, hlast1,
        P.flags + (size_t)(T_STEPS + t0) * FPS, P.claim + (size_t)(2 * c + 1) * 256, CT);
    // decoder
    gemmh<<<(CT * BB / 128) * (CC / 128), 256, 0, stream>>>(P.y1, P.wdec_h, b_dec,
                                                            out + (size_t)t0 * BB * CC,
                                                            CT * BB, CC, HH);
  }
}

// Round 18
// 3913.624 us; speedup vs baseline: 1.3554x; 1.1143x over previous
//
#include <hip/hip_runtime.h>

#define T_STEPS 512
#define BB 64
#define CC 256
#define HH 1024
#define TBROWS (T_STEPS*BB)      // 32768
#define BH (BB*HH)               // 65536
#define FLSTRIDE 32              // ints per flag line (128 B)
#define FPS (8*32*FLSTRIDE)      // flag ints per step (8 xcd x 32 slots)

typedef unsigned short u16;
typedef _Float16 f16;
typedef f16 f16x8 __attribute__((ext_vector_type(8)));
typedef float f32x4 __attribute__((ext_vector_type(4)));
typedef unsigned int u32x4 __attribute__((ext_vector_type(4)));
typedef unsigned int u32x2 __attribute__((ext_vector_type(2)));

__device__ __forceinline__ f32x4 mfma16h(f16x8 a, f16x8 b, f32x4 c) {
  return __builtin_amdgcn_mfma_f32_16x16x32_f16(a, b, c, 0, 0, 0);
}
__device__ __forceinline__ u16 f2h_bits(float f) {
  return __builtin_bit_cast(unsigned short, (f16)f);
}

__global__ void sentinel_kernel(float* o, float v) { o[0] = v; }

// ---------------- fp32 -> f16 single plane ----------------
__global__ __launch_bounds__(256) void cvt_h(const float* __restrict__ src,
                                             u16* __restrict__ dst, int n4) {
  int i = blockIdx.x * 256 + threadIdx.x;
  if (i >= n4) return;
  const float4 v = ((const float4*)src)[i];
  float vv[4] = {v.x, v.y, v.z, v.w};
  uint2 o;
  o.x = (unsigned)f2h_bits(vv[0]) | ((unsigned)f2h_bits(vv[1]) << 16);
  o.y = (unsigned)f2h_bits(vv[2]) | ((unsigned)f2h_bits(vv[3]) << 16);
  ((uint2*)dst)[i] = o;
}

__global__ __launch_bounds__(256) void add_bias_kernel(const float* __restrict__ a,
                                                       const float* __restrict__ b,
                                                       float* __restrict__ o, int n) {
  int i = blockIdx.x * 256 + threadIdx.x;
  if (i < n) o[i] = a[i] + b[i];
}

// ---------------- f16 GEMM: C[M,N] = A[M,K](f16) @ W[N,K](f16)^T + bias ----------------
__global__ __launch_bounds__(256) void gemmh(const u16* __restrict__ Ah,
                                             const u16* __restrict__ Wh,
                                             const float* __restrict__ bias,
                                             float* __restrict__ Cd,
                                             int M, int N, int K) {
  __shared__ u16 As[128][48];
  __shared__ u16 Bs[128][48];
  const int tid = threadIdx.x;
  const int nblk = N >> 7;
  const int mb = blockIdx.x / nblk;
  const int nb = blockIdx.x % nblk;
  const int m0 = mb << 7, n0 = nb << 7;
  const int lane = tid & 63, wave = tid >> 6;
  const int wm = (wave >> 1) * 64, wn = (wave & 1) * 64;
  const int fr = lane & 15, kg = lane >> 4;

  f32x4 acc[4][4];
#pragma unroll
  for (int i = 0; i < 4; ++i)
#pragma unroll
    for (int j = 0; j < 4; ++j) acc[i][j] = (f32x4){0.f, 0.f, 0.f, 0.f};

  const int sr = tid >> 1;
  const int sk = (tid & 1) * 16;

  for (int k0 = 0; k0 < K; k0 += 32) {
    __syncthreads();
    const size_t aoff = (size_t)(m0 + sr) * K + k0 + sk;
    *(uint4*)&As[sr][sk]     = *(const uint4*)(Ah + aoff);
    *(uint4*)&As[sr][sk + 8] = *(const uint4*)(Ah + aoff + 8);
    const size_t woff = (size_t)(n0 + sr) * K + k0 + sk;
    *(uint4*)&Bs[sr][sk]     = *(const uint4*)(Wh + woff);
    *(uint4*)&Bs[sr][sk + 8] = *(const uint4*)(Wh + woff + 8);
    __syncthreads();

    f16x8 ah[4], bh[4];
#pragma unroll
    for (int i = 0; i < 4; ++i) {
      ah[i] = *(const f16x8*)&As[wm + i * 16 + fr][kg * 8];
      bh[i] = *(const f16x8*)&Bs[wn + i * 16 + fr][kg * 8];
    }
#pragma unroll
    for (int i = 0; i < 4; ++i)
#pragma unroll
      for (int j = 0; j < 4; ++j)
        acc[i][j] = mfma16h(ah[i], bh[j], acc[i][j]);
  }

#pragma unroll
  for (int j = 0; j < 4; ++j) {
    const int n = n0 + wn + j * 16 + fr;
    const float bv = bias ? bias[n] : 0.f;
#pragma unroll
    for (int i = 0; i < 4; ++i) {
#pragma unroll
      for (int r = 0; r < 4; ++r) {
        const int m = m0 + wm + i * 16 + kg * 4 + r;
        Cd[(size_t)m * N + n] = acc[i][j][r] + bv;
      }
    }
  }
}

// ================= XCD-local scan kernel (used for BOTH layers) =================
// 256 WGs x 1024 threads, 1 WG/CU by LDS -> 32 WGs/XCD by capacity. WG claims
// (xcd, slot) via s_getreg(HW_REG_XCC_ID) + atomic. XCD x owns batches 8x..8x+8;
// slot s owns cols 32s..+32. All scan hops same-XCD: plain stores (local L2) +
// vmcnt(0) + flag; SLICE polling — wave q polls only its K-slice's producers.
// r18: layer 1's input projection (y0@W_ih1^T, no serial dependency) is
// extracted to a parallel GEMM (xw1), so this one kernel (K=1024, W_hh only,
// xw read in epilogue) serves both layers.

__device__ __forceinline__ int claim_role(int* claim, int* role_s, int tid) {
  if (tid == 0) {
    int xcd;
    asm volatile("s_getreg_b32 %0, hwreg(20, 0, 32)" : "=s"(xcd));  // HW_REG_XCC_ID
    xcd &= 7;
    int slot = __hip_atomic_fetch_add(claim + xcd * 32, 1, __ATOMIC_RELAXED,
                                      __HIP_MEMORY_SCOPE_AGENT) & 31;
    *role_s = xcd * 32 + slot;
  }
  __syncthreads();
  return *role_s;
}

// poll nf flag lines starting at base (lane i < nf checks line i)
__device__ __forceinline__ void poll_n(const int* base, int nf, int lane) {
  const int* p = base + (size_t)(lane & (nf - 1)) * FLSTRIDE;
  while (true) {
    int v = (lane < nf) ? __hip_atomic_load(p, __ATOMIC_RELAXED, __HIP_MEMORY_SCOPE_AGENT) : 1;
    if (__all(v != 0)) break;
    __builtin_amdgcn_s_sleep(1);
  }
}

__global__ __launch_bounds__(1024) void rnn_scan(
    const u16* __restrict__ Wh,                                 // W_hh [H][H] f16
    const u16* __restrict__ cin, u16* __restrict__ cout,        // [B][H] f16
    const float* __restrict__ xw,                               // [nsteps][B][H] f32 (bias incl.)
    u16* __restrict__ y,                                        // [nsteps][B][H] f16
    float* __restrict__ hlast,                                  // [B][H] f32
    int* __restrict__ flags, int* __restrict__ claim, int nsteps) {
  __shared__ u16 Ws[32][1024];         // 64 KB single-plane
  __shared__ f32x4 red[2][2][7][64];   // 28 KB (t&1, c2, q-1, lane)
  __shared__ int role_s, pcnt;

  const int tid = threadIdx.x;
  const int lane = tid & 63, wave = tid >> 6;
  const int c2 = wave & 1, q = wave >> 1;          // q: 0..7 (K=128 slice)
  const int fr = lane & 15, kg = lane >> 4;

  if (tid == 2) pcnt = 0;
  const int role = claim_role(claim, &role_s, tid);
  const int xcd = role >> 5, slot = role & 31;
  const int n0 = slot << 5;                        // 32 cols
  const int bb = (xcd << 3) + (fr & 7);            // global batch (fr>=8 duplicates)

  auto wsp = [&](int r, int cbyte) -> u16* {
    return (u16*)((char*)Ws + (size_t)r * 2048 + (cbyte ^ ((r & 7) << 4)));
  };
  {  // stage 64 KB: 1024 threads x 64 B
#pragma unroll
    for (int j = 0; j < 4; ++j) {
      const int off = tid * 64 + j * 16;
      const int row = off >> 11;                   // 0..31
      const int cbyte = off & 2047;
      const u16* src = Wh + (size_t)(n0 + row) * HH + (cbyte >> 1);
      *(uint4*)wsp(row, cbyte) = *(const uint4*)src;
    }
  }
  __syncthreads();

  const int co = n0 + c2 * 16 + (kg << 2);         // epilogue col base (q==0)
  const size_t hoff = (size_t)bb * HH + q * 128 + (kg << 3);
  const int wrow = c2 * 16 + fr;                   // W row for A-fragment

  for (int t = 0; t < nsteps; ++t) {
    const size_t obase = (size_t)t * BH;
    float4 xwv;
    if (q == 0 && fr < 8) xwv = *(const float4*)(xw + obase + (size_t)bb * HH + co);

    // slice-poll: wave q needs cols q*128..+128 -> slots q*4..q*4+4
    if (t > 0)
      poll_n(flags + (((size_t)(t - 1) * 8 + xcd) * 32 + q * 4) * FLSTRIDE, 4, lane);
    __atomic_signal_fence(__ATOMIC_ACQUIRE);

    const u16* pb = ((t == 0) ? cin : (y + (size_t)(t - 1) * BH)) + hoff;

    u32x4 hv[4];
#pragma unroll
    for (int kc = 0; kc < 4; ++kc)
      asm volatile("global_load_dwordx4 %0, %1, off offset:%2"
                   : "=v"(hv[kc]) : "v"(pb), "i"(kc * 64));
    asm volatile("s_waitcnt vmcnt(0)" ::: "memory");
    __builtin_amdgcn_sched_barrier(0);

    f32x4 acc0 = (f32x4){0.f, 0.f, 0.f, 0.f}, acc1 = acc0;
#pragma unroll
    for (int kc = 0; kc < 4; ++kc) {
      f16x8 hb = __builtin_bit_cast(f16x8, hv[kc]);
      const int cb = q * 256 + kc * 64 + kg * 16;
      f16x8 wh = *(const f16x8*)wsp(wrow, cb);
      if (kc & 1) acc1 = mfma16h(wh, hb, acc1); else acc0 = mfma16h(wh, hb, acc0);
    }
    f32x4 accv = acc0 + acc1;

    if (q != 0) red[t & 1][c2][q - 1][lane] = accv;
    __syncthreads();                               // barrier B (only barrier/round)

    if (q == 0) {
#pragma unroll
      for (int i = 0; i < 7; ++i) accv += red[t & 1][c2][i][lane];
      float hvv[4]; u16 qb[4];
#pragma unroll
      for (int r = 0; r < 4; ++r) {
        hvv[r] = tanhf(accv[r] + ((const float*)&xwv)[r]);
        qb[r] = f2h_bits(hvv[r]);
      }
      if (fr < 8) {
        const size_t oi = obase + (size_t)bb * HH + co;
        u32x2 hp;
        hp.x = (unsigned)qb[0] | ((unsigned)qb[1] << 16);
        hp.y = (unsigned)qb[2] | ((unsigned)qb[3] << 16);
        *(u32x2*)(y + oi) = hp;                    // plain store -> local L2
        if (t == nsteps - 1) {
          *(u32x2*)(cout + (size_t)bb * HH + co) = hp;
          *(float4*)(hlast + (size_t)bb * HH + co) = (float4){hvv[0], hvv[1], hvv[2], hvv[3]};
        }
      }
      asm volatile("s_waitcnt vmcnt(0)" ::: "memory");   // y at L2
      if (lane == 0) {
        int old = __hip_atomic_fetch_add(&pcnt, 1, __ATOMIC_ACQ_REL, __HIP_MEMORY_SCOPE_WORKGROUP);
        if (old & 1) {  // second of the two c2 epilogue waves publishes
          int* fp = flags + (((size_t)t * 8 + xcd) * 32 + slot) * FLSTRIDE;
          __hip_atomic_store(fp, 1, __ATOMIC_RELAXED, __HIP_MEMORY_SCOPE_AGENT);
        }
      }
    }
  }
}

// ---------------- host ----------------
struct Ptrs {
  u16 *wih0_h, *whh0_h, *wih1_h, *whh1_h, *wdec_h;
  float *b0, *b1;
  u16 *carA, *carB;       // [2*BH] f16
  int* flags;             // [2*T_STEPS][FPS]
  int* claim;             // [128][8][32]
  u16 *x_h;               // [CT*BB*CC]
  float* xw;              // [CT*BH] (xw0, later overwritten by xw1)
  u16 *y0, *y1;           // [CT*BH]
  size_t total;
};

static Ptrs make_plan(char* base, int CT) {
  Ptrs p;
  size_t off = 0;
  auto take = [&](size_t bytes) -> char* {
    off = (off + 255) & ~(size_t)255;
    char* q = base + off;
    off += bytes;
    return q;
  };
  p.wih0_h  = (u16*)take((size_t)HH * CC * 2);
  p.whh0_h  = (u16*)take((size_t)HH * HH * 2);
  p.wih1_h  = (u16*)take((size_t)HH * HH * 2);
  p.whh1_h  = (u16*)take((size_t)HH * HH * 2);
  p.wdec_h  = (u16*)take((size_t)CC * HH * 2);
  p.b0      = (float*)take((size_t)HH * 4);
  p.b1      = (float*)take((size_t)HH * 4);
  p.carA    = (u16*)take((size_t)2 * BH * 2);
  p.carB    = (u16*)take((size_t)2 * BH * 2);
  p.flags   = (int*)take((size_t)2 * T_STEPS * FPS * 4);
  p.claim   = (int*)take((size_t)128 * 8 * 32 * 4);
  p.x_h     = (u16*)take((size_t)CT * BB * CC * 2);
  p.xw      = (float*)take((size_t)CT * BH * 4);
  p.y0      = (u16*)take((size_t)CT * BH * 2);
  p.y1      = (u16*)take((size_t)CT * BH * 2);
  p.total   = off;
  return p;
}

extern "C" void kernel_launch(void* const* d_in, const int* in_sizes, int n_in,
                              void* d_out, int out_size, void* d_ws, size_t ws_size,
                              hipStream_t stream) {
  (void)in_sizes; (void)n_in; (void)out_size;
  const float* x     = (const float*)d_in[0];
  const float* h0    = (const float*)d_in[1];
  const float* w_ih0 = (const float*)d_in[2];
  const float* w_hh0 = (const float*)d_in[3];
  const float* b_ih0 = (const float*)d_in[4];
  const float* b_hh0 = (const float*)d_in[5];
  const float* w_ih1 = (const float*)d_in[6];
  const float* w_hh1 = (const float*)d_in[7];
  const float* b_ih1 = (const float*)d_in[8];
  const float* b_hh1 = (const float*)d_in[9];
  const float* w_dec = (const float*)d_in[10];
  const float* b_dec = (const float*)d_in[11];
  float* out = (float*)d_out;

  int CT = T_STEPS;
  Ptrs P = make_plan((char*)d_ws, CT);
  while (P.total > ws_size && CT > 8) {
    CT >>= 1;
    P = make_plan((char*)d_ws, CT);
  }
  if (P.total > ws_size) {
    sentinel_kernel<<<1, 1, 0, stream>>>(out, (float)ws_size);
    return;
  }
  const int NCH = T_STEPS / CT;

  (void)hipMemsetAsync(P.flags, 0, (size_t)2 * T_STEPS * FPS * 4, stream);
  (void)hipMemsetAsync(P.claim, 0, (size_t)128 * 8 * 32 * 4, stream);

  // one-time weight/bias/h0 prep (all single-plane f16)
  cvt_h<<<HH * CC / 1024, 256, 0, stream>>>(w_ih0, P.wih0_h, HH * CC / 4);
  cvt_h<<<HH * HH / 1024, 256, 0, stream>>>(w_hh0, P.whh0_h, HH * HH / 4);
  cvt_h<<<HH * HH / 1024, 256, 0, stream>>>(w_ih1, P.wih1_h, HH * HH / 4);
  cvt_h<<<HH * HH / 1024, 256, 0, stream>>>(w_hh1, P.whh1_h, HH * HH / 4);
  cvt_h<<<CC * HH / 1024, 256, 0, stream>>>(w_dec, P.wdec_h, CC * HH / 4);
  cvt_h<<<2 * BH / 1024, 256, 0, stream>>>(h0, P.carA, 2 * BH / 4);
  add_bias_kernel<<<HH / 256, 256, 0, stream>>>(b_ih0, b_hh0, P.b0, HH);
  add_bias_kernel<<<HH / 256, 256, 0, stream>>>(b_ih1, b_hh1, P.b1, HH);

  float* hlast0 = out + (size_t)TBROWS * CC;
  float* hlast1 = hlast0 + BH;

  for (int c = 0; c < NCH; ++c) {
    const int t0 = c * CT;
    const u16* cin = (c & 1) ? P.carB : P.carA;
    u16* cout = (c & 1) ? P.carA : P.carB;

    cvt_h<<<CT * BB * CC / 1024, 256, 0, stream>>>(x + (size_t)t0 * BB * CC, P.x_h,
                                                   CT * BB * CC / 4);
    // xw0 = x @ W_ih0^T + (b_ih0+b_hh0)
    gemmh<<<(CT * BB / 128) * (HH / 128), 256, 0, stream>>>(P.x_h, P.wih0_h, P.b0, P.xw,
                                                            CT * BB, HH, CC);
    // layer-0 scan (XCD-local)
    rnn_scan<<<256, 1024, 0, stream>>>(
        P.whh0_h, cin, cout, P.xw, P.y0, hlast0,
        P.flags + (size_t)t0 * FPS, P.claim + (size_t)(2 * c) * 256, CT);
    // xw1 = y0 @ W_ih1^T + (b_ih1+b_hh1)  — dependency-free, extracted from scan
    // (overwrites P.xw; scanA has finished reading it)
    gemmh<<<(CT * BB / 128) * (HH / 128), 256, 0, stream>>>(P.y0, P.wih1_h, P.b1, P.xw,
                                                            CT * BB, HH, HH);
    // layer-1 scan — same kernel, same shape as layer 0
    rnn_scan<<<256, 1024, 0, stream>>>(
        P.whh1_h, cin + BH, cout + BH, P.xw, P.y1, hlast1,
        P.flags + (size_t)(T_STEPS + t0) * FPS, P.claim + (size_t)(2 * c + 1) * 256, CT);
    // decoder
    gemmh<<<(CT * BB / 128) * (CC / 128), 256, 0, stream>>>(P.y1, P.wdec_h, b_dec,
                                                            out + (size_t)t0 * BB * CC,
                                                            CT * BB, CC, HH);
  }
}